// Round 2
// baseline (313.285 us; speedup 1.0000x reference)
//
#include <hip/hip_runtime.h>

#define DEV __device__ __forceinline__

typedef __bf16 bf16x8 __attribute__((ext_vector_type(8)));
typedef float f32x4 __attribute__((ext_vector_type(4)));

// ---------- helpers ----------
DEV float blo(unsigned u) { return __builtin_bit_cast(float, u << 16); }
DEV float bhi(unsigned u) { return __builtin_bit_cast(float, u & 0xFFFF0000u); }
DEV unsigned short f2b(float f) {
  unsigned u = __builtin_bit_cast(unsigned, f);
  return (unsigned short)((u + 0x7FFFu + ((u >> 16) & 1u)) >> 16);
}
DEV float sigf(float x) { return 1.0f / (1.0f + expf(-x)); }

DEV void llds16(const void* g, void* l) {
  __builtin_amdgcn_global_load_lds(
      (__attribute__((address_space(1))) void*)(void*)g,
      (__attribute__((address_space(3))) void*)l, 16, 0, 0);
}

DEV void unpack8(uint4 u, float* d) {
  d[0] = blo(u.x); d[1] = bhi(u.x); d[2] = blo(u.y); d[3] = bhi(u.y);
  d[4] = blo(u.z); d[5] = bhi(u.z); d[6] = blo(u.w); d[7] = bhi(u.w);
}

// ---------- fp32 -> bf16 conversion ----------
__global__ __launch_bounds__(256) void cvt_bf16_kernel(
    const float* __restrict__ src, unsigned short* __restrict__ dst, int n4) {
  int i = blockIdx.x * 256 + threadIdx.x;
  if (i < n4) {
    float4 f = ((const float4*)src)[i];
    ushort4 o;
    o.x = f2b(f.x); o.y = f2b(f.y); o.z = f2b(f.z); o.w = f2b(f.w);
    ((ushort4*)dst)[i] = o;
  }
}

// ---------- 256x256 8-wave phase-interleaved GEMM ----------
// C[m][n] = sum_k A[m][k]*B[n][k], both row-major bf16.  BK=64, 2-slot LDS dbuf,
// counted vmcnt, XOR bank swizzle (slot ^= row&7) pre-applied on global source.
// Race-free invariant: all ds_reads of tile t issue in phases 0-1 (ks1 frags
// held in regs); phases 2-3 prefetch tile t+2 into the same slot AFTER the
// end-of-phase-1 barrier guarantees every wave's reads completed.
// Columns >= act_col0 get v = tanh(v + bias[col-act_col0]).
template <int OUTF>  // 0 = bf16 out, 1 = fp32 out
__global__ __launch_bounds__(512, 2) void gemm8p_kernel(
    const unsigned short* __restrict__ A, const unsigned short* __restrict__ B,
    void* __restrict__ Cout, int M, int N, int K, int act_col0,
    const float* __restrict__ bias, int nbn) {
  __shared__ char lds[2][4][16384];  // [slot][Atop,Abot,Btop,Bbot][16KB]
  const int tid = threadIdx.x;
  const int l = tid & 63;
  const int w = tid >> 6;           // 0..7
  const int wm = w >> 2, wn = w & 3;
  const int ln15 = l & 15, hi = l >> 4;

  // bijective XCD swizzle (m204), then bn-fast decomposition (A-panel reuse)
  const int nwg = gridDim.x;
  const int orig = blockIdx.x;
  const int qd = nwg >> 3, rm = nwg & 7;
  const int xcd = orig & 7, loc = orig >> 3;
  const int swz = (xcd < rm ? xcd * (qd + 1) : rm * (qd + 1) + (xcd - rm) * qd) + loc;
  const int bn = swz % nbn, bm = swz / nbn;
  const int m0 = bm * 256, n0 = bn * 256;

  // stage one 128-row x 64-col half-tile chunk pair for this wave
  auto stage = [&](const unsigned short* src, int row0, int k0, char* unit) {
#pragma unroll
    for (int j = 0; j < 2; ++j) {
      const int c = w * 2 + j;                 // chunk 0..15, wave-uniform
      const int rr = c * 8 + (l >> 3);         // row 0..127
      const int slot = (l & 7) ^ (rr & 7);     // inverse swizzle on source
      llds16(src + (size_t)(row0 + rr) * K + k0 + slot * 8, unit + c * 1024);
    }
  };
  auto rdA = [&](const char* unit, int rb, int ks) -> bf16x8 {
    const int row = rb * 16 + ln15;
    const int slot = (ks * 4 + hi) ^ (row & 7);
    return *(const bf16x8*)(unit + row * 128 + slot * 16);
  };
  auto rdB = [&](const char* unit, int cf, int ks) -> bf16x8 {
    const int row = (wn & 1) * 64 + cf * 16 + ln15;
    const int slot = (ks * 4 + hi) ^ (row & 7);
    return *(const bf16x8*)(unit + row * 128 + slot * 16);
  };

  f32x4 acc[8][4] = {};
  const int KT = K >> 6;

  // prologue: stage tiles 0 and 1 (8 wave-loads each; tile0's are oldest)
#pragma unroll
  for (int t = 0; t < 2; ++t) {
    stage(A, m0,       t * 64, (char*)lds[t][0]);
    stage(A, m0 + 128, t * 64, (char*)lds[t][1]);
    stage(B, n0,       t * 64, (char*)lds[t][2]);
    stage(B, n0 + 128, t * 64, (char*)lds[t][3]);
  }

  for (int t = 0; t < KT; ++t) {
    const int s = t & 1;
    if (t < KT - 1) asm volatile("s_waitcnt vmcnt(8)" ::: "memory");
    else            asm volatile("s_waitcnt vmcnt(0)" ::: "memory");
    __builtin_amdgcn_s_barrier();
    const char* Au = lds[s][wm];
    const char* Bu = lds[s][2 + (wn >> 1)];
    bf16x8 A0[4], A1[4], A2[4], A3[4], B0[4], B1[4];

    // ---- phase 0: read rows 0-63 (both k-slices) + B ks0; MFMA (rh0, ks0)
#pragma unroll
    for (int i = 0; i < 4; ++i) { A0[i] = rdA(Au, i, 0); A1[i] = rdA(Au, i, 1); }
#pragma unroll
    for (int j = 0; j < 4; ++j) B0[j] = rdB(Bu, j, 0);
    __builtin_amdgcn_s_barrier();
    asm volatile("s_waitcnt lgkmcnt(0)" ::: "memory");
    __builtin_amdgcn_sched_barrier(0);
    __builtin_amdgcn_s_setprio(1);
#pragma unroll
    for (int i = 0; i < 4; ++i)
#pragma unroll
      for (int j = 0; j < 4; ++j)
        acc[i][j] = __builtin_amdgcn_mfma_f32_16x16x32_bf16(A0[i], B0[j], acc[i][j], 0, 0, 0);
    __builtin_amdgcn_s_setprio(0);
    __builtin_amdgcn_s_barrier();

    // ---- phase 1: read rows 64-127 (both k-slices) + B ks1; MFMA (rh1, ks0)
#pragma unroll
    for (int i = 0; i < 4; ++i) { A2[i] = rdA(Au, 4 + i, 0); A3[i] = rdA(Au, 4 + i, 1); }
#pragma unroll
    for (int j = 0; j < 4; ++j) B1[j] = rdB(Bu, j, 1);
    __builtin_amdgcn_s_barrier();
    asm volatile("s_waitcnt lgkmcnt(0)" ::: "memory");
    __builtin_amdgcn_sched_barrier(0);
    __builtin_amdgcn_s_setprio(1);
#pragma unroll
    for (int i = 0; i < 4; ++i)
#pragma unroll
      for (int j = 0; j < 4; ++j)
        acc[4 + i][j] = __builtin_amdgcn_mfma_f32_16x16x32_bf16(A2[i], B0[j], acc[4 + i][j], 0, 0, 0);
    __builtin_amdgcn_s_setprio(0);
    __builtin_amdgcn_s_barrier();

    // ---- phase 2: prefetch A halves of tile t+2 into this slot; MFMA (rh0, ks1)
    if (t + 2 < KT) {
      stage(A, m0,       (t + 2) * 64, (char*)lds[s][0]);
      stage(A, m0 + 128, (t + 2) * 64, (char*)lds[s][1]);
    }
    __builtin_amdgcn_s_barrier();
    __builtin_amdgcn_s_setprio(1);
#pragma unroll
    for (int i = 0; i < 4; ++i)
#pragma unroll
      for (int j = 0; j < 4; ++j)
        acc[i][j] = __builtin_amdgcn_mfma_f32_16x16x32_bf16(A1[i], B1[j], acc[i][j], 0, 0, 0);
    __builtin_amdgcn_s_setprio(0);
    __builtin_amdgcn_s_barrier();

    // ---- phase 3: prefetch B halves of tile t+2; MFMA (rh1, ks1)
    if (t + 2 < KT) {
      stage(B, n0,       (t + 2) * 64, (char*)lds[s][2]);
      stage(B, n0 + 128, (t + 2) * 64, (char*)lds[s][3]);
    }
    __builtin_amdgcn_s_barrier();
    __builtin_amdgcn_s_setprio(1);
#pragma unroll
    for (int i = 0; i < 4; ++i)
#pragma unroll
      for (int j = 0; j < 4; ++j)
        acc[4 + i][j] = __builtin_amdgcn_mfma_f32_16x16x32_bf16(A3[i], B1[j], acc[4 + i][j], 0, 0, 0);
    __builtin_amdgcn_s_setprio(0);
    // tile-boundary vmcnt + barrier at top of next iteration
  }

  // epilogue: C/D layout col=lane&15, row=(lane>>4)*4+reg
#pragma unroll
  for (int i = 0; i < 8; ++i) {
    const int rowb = m0 + wm * 128 + i * 16 + hi * 4;
#pragma unroll
    for (int j = 0; j < 4; ++j) {
      const int col = n0 + wn * 64 + j * 16 + ln15;
#pragma unroll
      for (int r = 0; r < 4; ++r) {
        float v = acc[i][j][r];
        if (col >= act_col0) v = tanhf(v + bias[col - act_col0]);
        const size_t off = (size_t)(rowb + r) * N + col;
        if (OUTF == 0) ((unsigned short*)Cout)[off] = f2b(v);
        else ((float*)Cout)[off] = v;
      }
    }
  }
}

// ---------- sensor layer 2: lc = sigmoid(h1 @ w2.T + b2) ----------
__global__ __launch_bounds__(256) void sensor2_kernel(
    const unsigned short* __restrict__ QKVH, const float* __restrict__ w2,
    const float* __restrict__ b2, float* __restrict__ LC) {
  const int tid = threadIdx.x;
  const int h = tid & 15, r = tid >> 4;
  const int m = blockIdx.x * 16 + r;
  const unsigned short* hrow = QKVH + (size_t)m * 3328 + 3072;
  const float* wrow = w2 + h * 256;
  float acc = 0.0f;
  for (int d = 0; d < 256; d += 8) {
    uint4 hv = *(const uint4*)(hrow + d);
    float4 wa = *(const float4*)(wrow + d);
    float4 wb = *(const float4*)(wrow + d + 4);
    acc = fmaf(blo(hv.x), wa.x, acc); acc = fmaf(bhi(hv.x), wa.y, acc);
    acc = fmaf(blo(hv.y), wa.z, acc); acc = fmaf(bhi(hv.y), wa.w, acc);
    acc = fmaf(blo(hv.z), wb.x, acc); acc = fmaf(bhi(hv.z), wb.y, acc);
    acc = fmaf(blo(hv.w), wb.z, acc); acc = fmaf(bhi(hv.w), wb.w, acc);
  }
  LC[(size_t)m * 16 + h] = sigf(acc + b2[h]);
}

// ---------- scan pass A: per-chunk scan from zero -> M (fp32), P = prod(lam) ----------
__global__ __launch_bounds__(256) void scan_passA_kernel(
    const unsigned short* __restrict__ QKVH, const float* __restrict__ LC,
    const float* __restrict__ decay, float* __restrict__ MS, float* __restrict__ P) {
  __shared__ unsigned short kL[4096], vL[4096];
  __shared__ float lamL[4096];
  __shared__ float sigL[64], lcL[64];
  const int tid = threadIdx.x;
  const int c = blockIdx.x, h = blockIdx.y, b = blockIdx.z;
  const int t0 = c * 64;
  const int eg = tid & 3, fo = tid >> 2, e0 = eg * 16;

#pragma unroll
  for (int i = 0; i < 2; ++i) {
    int idx = i * 256 + tid;
    int row = idx >> 3, ch = idx & 7;
    size_t g = (size_t)(b * 2048 + t0 + row) * 3328 + h * 64 + ch * 8;
    int lb = (i * 256 + (tid >> 6) * 64) * 16;
    llds16(QKVH + g + 1024, (char*)kL + lb);
    llds16(QKVH + g + 2048, (char*)vL + lb);
  }
  if (tid < 64) sigL[tid] = sigf(decay[h * 64 + tid]);
  else if (tid < 128) lcL[tid - 64] = LC[(size_t)(b * 2048 + t0 + tid - 64) * 16 + h];
  __syncthreads();
#pragma unroll
  for (int i = 0; i < 16; ++i) {
    int idx = i * 256 + tid;
    lamL[idx] = fminf(sigL[idx & 63] * (1.0f + 0.2f * lcL[idx >> 6]), 0.9995f);
  }
  __syncthreads();

  float S[16], Pr[16];
#pragma unroll
  for (int i = 0; i < 16; ++i) { S[i] = 0.0f; Pr[i] = 1.0f; }

  for (int t = 0; t < 64; ++t) {
    float lam[16], kk[16];
#pragma unroll
    for (int j = 0; j < 4; ++j) {
      f32x4 l4 = *(const f32x4*)&lamL[t * 64 + e0 + j * 4];
      lam[j * 4 + 0] = l4[0]; lam[j * 4 + 1] = l4[1];
      lam[j * 4 + 2] = l4[2]; lam[j * 4 + 3] = l4[3];
    }
    uint4 k0 = *(const uint4*)&kL[t * 64 + e0];
    uint4 k1 = *(const uint4*)&kL[t * 64 + e0 + 8];
    unpack8(k0, kk); unpack8(k1, kk + 8);
    float vf = blo((unsigned)vL[t * 64 + fo]);
#pragma unroll
    for (int i = 0; i < 16; ++i) {
      S[i] = fmaf(S[i], lam[i], kk[i] * vf);
      Pr[i] *= lam[i];
    }
  }
  size_t slot = (size_t)((b * 16 + h) * 32 + c);
  float* Mp = MS + slot * 4096;
#pragma unroll
  for (int i = 0; i < 16; ++i) Mp[(e0 + i) * 64 + fo] = S[i];
  if (fo == 0) {
#pragma unroll
    for (int i = 0; i < 16; ++i) P[slot * 64 + e0 + i] = Pr[i];
  }
}

// ---------- scan pass B: chunk-state composition, elementwise-parallel ----------
// S[e,f] recurrence is independent per (bh,e,f): 64*4096 threads, 32 steps each.
__global__ __launch_bounds__(256) void scan_passB_kernel(
    float* __restrict__ MS, const float* __restrict__ P) {
  const int bh = blockIdx.y;
  const int ef = blockIdx.x * 256 + threadIdx.x;  // 0..4095
  const int e = ef >> 6;
  const size_t base = (size_t)bh * 32;
  float S = 0.0f;
  for (int c = 0; c < 32; ++c) {
    float* Mp = MS + (base + c) * 4096 + ef;
    const float p = P[(base + c) * 64 + e];
    const float m = *Mp;
    *Mp = S;                 // store S_in(c)
    S = fmaf(p, S, m);       // advance
  }
}

// ---------- scan pass C: re-run chunk from true S_in, emit y ----------
__global__ __launch_bounds__(256) void scan_passC_kernel(
    const unsigned short* __restrict__ QKVH, const float* __restrict__ LC,
    const float* __restrict__ decay, const float* __restrict__ MS,
    unsigned short* __restrict__ Y) {
  __shared__ unsigned short qL[4096], kL[4096], vL[4096];
  __shared__ float lamL[4096];
  __shared__ float sigL[64], lcL[64];
  const int tid = threadIdx.x;
  const int c = blockIdx.x, h = blockIdx.y, b = blockIdx.z;
  const int t0 = c * 64;
  const int eg = tid & 3, fo = tid >> 2, e0 = eg * 16;

#pragma unroll
  for (int i = 0; i < 2; ++i) {
    int idx = i * 256 + tid;
    int row = idx >> 3, ch = idx & 7;
    size_t g = (size_t)(b * 2048 + t0 + row) * 3328 + h * 64 + ch * 8;
    int lb = (i * 256 + (tid >> 6) * 64) * 16;
    llds16(QKVH + g,        (char*)qL + lb);
    llds16(QKVH + g + 1024, (char*)kL + lb);
    llds16(QKVH + g + 2048, (char*)vL + lb);
  }
  if (tid < 64) sigL[tid] = sigf(decay[h * 64 + tid]);
  else if (tid < 128) lcL[tid - 64] = LC[(size_t)(b * 2048 + t0 + tid - 64) * 16 + h];
  __syncthreads();
#pragma unroll
  for (int i = 0; i < 16; ++i) {
    int idx = i * 256 + tid;
    lamL[idx] = fminf(sigL[idx & 63] * (1.0f + 0.2f * lcL[idx >> 6]), 0.9995f);
  }
  const float* Sp = MS + ((size_t)((b * 16 + h) * 32 + c)) * 4096;
  float S[16];
#pragma unroll
  for (int i = 0; i < 16; ++i) S[i] = Sp[(e0 + i) * 64 + fo];
  __syncthreads();

  unsigned short* Yp = Y + (size_t)(b * 2048 + t0) * 1024 + h * 64 + fo;
  for (int t = 0; t < 64; ++t) {
    float lam[16], kk[16], qq[16];
#pragma unroll
    for (int j = 0; j < 4; ++j) {
      f32x4 l4 = *(const f32x4*)&lamL[t * 64 + e0 + j * 4];
      lam[j * 4 + 0] = l4[0]; lam[j * 4 + 1] = l4[1];
      lam[j * 4 + 2] = l4[2]; lam[j * 4 + 3] = l4[3];
    }
    uint4 k0 = *(const uint4*)&kL[t * 64 + e0];
    uint4 k1 = *(const uint4*)&kL[t * 64 + e0 + 8];
    unpack8(k0, kk); unpack8(k1, kk + 8);
    uint4 q0 = *(const uint4*)&qL[t * 64 + e0];
    uint4 q1 = *(const uint4*)&qL[t * 64 + e0 + 8];
    unpack8(q0, qq); unpack8(q1, qq + 8);
    float vf = blo((unsigned)vL[t * 64 + fo]);
    float acc = 0.0f;
#pragma unroll
    for (int i = 0; i < 16; ++i) {
      S[i] = fmaf(S[i], lam[i], kk[i] * vf);
      acc = fmaf(qq[i], S[i], acc);
    }
    acc += __shfl_xor(acc, 1);
    acc += __shfl_xor(acc, 2);
    if (eg == 0) Yp[(size_t)t * 1024] = f2b(acc);
  }
}

// ---------- host launch ----------
extern "C" void kernel_launch(void* const* d_in, const int* in_sizes, int n_in,
                              void* d_out, int out_size, void* d_ws, size_t ws_size,
                              hipStream_t stream) {
  (void)in_sizes; (void)n_in; (void)out_size; (void)ws_size;
  const float* x     = (const float*)d_in[0];
  const float* q_w   = (const float*)d_in[1];
  const float* k_w   = (const float*)d_in[2];
  const float* v_w   = (const float*)d_in[3];
  const float* o_w   = (const float*)d_in[4];
  const float* cs_w1 = (const float*)d_in[5];
  const float* cs_b1 = (const float*)d_in[6];
  const float* cs_w2 = (const float*)d_in[7];
  const float* cs_b2 = (const float*)d_in[8];
  const float* decay = (const float*)d_in[9];
  float* out = (float*)d_out;

  char* ws = (char*)d_ws;
  unsigned short* XB   = (unsigned short*)(ws);                 // 16,777,216 B
  unsigned short* WCAT = (unsigned short*)(ws + 16777216);      //  6,815,744 B
  unsigned short* OWB  = (unsigned short*)(ws + 23592960);      //  2,097,152 B
  unsigned short* QKVH = (unsigned short*)(ws + 25690112);      // 54,525,952 B
  float*          LCb  = (float*)(ws + 80216064);               //    524,288 B
  float*          MS   = (float*)(ws + 80740352);               // 33,554,432 B
  float*          Pb   = (float*)(ws + 114294784);              //    524,288 B
  unsigned short* YB   = (unsigned short*)(ws + 114819072);     // 16,777,216 B

  // 1) bf16 conversions
  cvt_bf16_kernel<<<8192, 256, 0, stream>>>(x, XB, 2097152);
  cvt_bf16_kernel<<<1024, 256, 0, stream>>>(q_w, WCAT, 262144);
  cvt_bf16_kernel<<<1024, 256, 0, stream>>>(k_w, WCAT + 1048576, 262144);
  cvt_bf16_kernel<<<1024, 256, 0, stream>>>(v_w, WCAT + 2097152, 262144);
  cvt_bf16_kernel<<<256,  256, 0, stream>>>(cs_w1, WCAT + 3145728, 65536);
  cvt_bf16_kernel<<<1024, 256, 0, stream>>>(o_w, OWB, 262144);

  // 2) fused q|k|v|h1 GEMM: [8192x1024] @ [3328x1024]^T, tanh+bias on cols >=3072
  gemm8p_kernel<0><<<416, 512, 0, stream>>>(XB, WCAT, QKVH, 8192, 3328,
                                            1024, 3072, cs_b1, 13);
  // 3) sensor layer 2 -> lc
  sensor2_kernel<<<512, 256, 0, stream>>>(QKVH, cs_w2, cs_b2, LCb);

  // 4) chunked scan (L=64, C=32)
  scan_passA_kernel<<<dim3(32, 16, 4), 256, 0, stream>>>(QKVH, LCb, decay, MS, Pb);
  scan_passB_kernel<<<dim3(16, 64), 256, 0, stream>>>(MS, Pb);
  scan_passC_kernel<<<dim3(32, 16, 4), 256, 0, stream>>>(QKVH, LCb, decay, MS, YB);

  // 5) o-projection: [8192x1024] @ [1024x1024]^T -> fp32 out
  gemm8p_kernel<1><<<128, 512, 0, stream>>>(YB, OWB, out, 8192, 1024,
                                            1024, 1 << 30, nullptr, 4);
}

// Round 3
// 292.016 us; speedup vs baseline: 1.0728x; 1.0728x over previous
//
#include <hip/hip_runtime.h>

#define DEV __device__ __forceinline__
#define MFMA(a, b, c) __builtin_amdgcn_mfma_f32_16x16x32_bf16(a, b, c, 0, 0, 0)

typedef __bf16 bf16x8 __attribute__((ext_vector_type(8)));
typedef float f32x4 __attribute__((ext_vector_type(4)));

// ---------- helpers ----------
DEV float blo(unsigned u) { return __builtin_bit_cast(float, u << 16); }
DEV float bhi(unsigned u) { return __builtin_bit_cast(float, u & 0xFFFF0000u); }
DEV unsigned short f2b(float f) {
  unsigned u = __builtin_bit_cast(unsigned, f);
  return (unsigned short)((u + 0x7FFFu + ((u >> 16) & 1u)) >> 16);
}
DEV float sigf(float x) { return 1.0f / (1.0f + expf(-x)); }

DEV void llds16(const void* g, void* l) {
  __builtin_amdgcn_global_load_lds(
      (__attribute__((address_space(1))) void*)(void*)g,
      (__attribute__((address_space(3))) void*)l, 16, 0, 0);
}

DEV void unpack8(uint4 u, float* d) {
  d[0] = blo(u.x); d[1] = bhi(u.x); d[2] = blo(u.y); d[3] = bhi(u.y);
  d[4] = blo(u.z); d[5] = bhi(u.z); d[6] = blo(u.w); d[7] = bhi(u.w);
}

// ---------- fused fp32 -> bf16 conversion (all 6 tensors, 1 launch) ----------
__global__ __launch_bounds__(256) void cvt_all_kernel(
    const float* __restrict__ x, const float* __restrict__ qw,
    const float* __restrict__ kw, const float* __restrict__ vw,
    const float* __restrict__ cw1, const float* __restrict__ ow,
    unsigned short* __restrict__ XB, unsigned short* __restrict__ WCAT,
    unsigned short* __restrict__ OWB) {
  const int i = blockIdx.x * 256 + threadIdx.x;
  const float* s;
  unsigned short* d;
  if (i < 2097152)      { s = x   + (size_t)i * 4;                 d = XB + (size_t)i * 4; }
  else if (i < 2359296) { size_t j = i - 2097152; s = qw  + j * 4; d = WCAT + j * 4; }
  else if (i < 2621440) { size_t j = i - 2359296; s = kw  + j * 4; d = WCAT + 1048576 + j * 4; }
  else if (i < 2883584) { size_t j = i - 2621440; s = vw  + j * 4; d = WCAT + 2097152 + j * 4; }
  else if (i < 2949120) { size_t j = i - 2883584; s = cw1 + j * 4; d = WCAT + 3145728 + j * 4; }
  else if (i < 3211264) { size_t j = i - 2949120; s = ow  + j * 4; d = OWB + j * 4; }
  else return;
  float4 f = *(const float4*)s;
  ushort4 o;
  o.x = f2b(f.x); o.y = f2b(f.y); o.z = f2b(f.z); o.w = f2b(f.w);
  *(ushort4*)d = o;
}

// ---------- 256x256 8-phase GEMM (faithful m201-style schedule) ----------
// C[m][n] = sum_k A[m][k]*B[n][k], row-major bf16. BK=64, 2-slot x 4-unit LDS
// (unit = 128x64 half-tile, 16KiB). Per 2 K-tiles: 8 phases, each =
// {ds_read quadrant frags + stage 1 unit + barrier + lgkm(0) + 16 MFMA + barrier}.
// vmcnt(4) only at ends of phases 3 and 7. XOR swizzle kc^=(row&7) both sides.
template <int OUTF>
__global__ __launch_bounds__(512, 2) void gemm8p_kernel(
    const unsigned short* __restrict__ A, const unsigned short* __restrict__ B,
    void* __restrict__ Cout, int M, int N, int K, int act_col0,
    const float* __restrict__ bias, int nbn) {
  __shared__ char lds[2][4][16384];  // [slot][Atop,Abot,Btop,Bbot]
  const int tid = threadIdx.x;
  const int l = tid & 63, w = tid >> 6;
  const int wm = w >> 2, wn = w & 3;
  const int ln15 = l & 15, hi = l >> 4;

  const int nwg = gridDim.x, orig = blockIdx.x;
  const int qd = nwg >> 3, rm = nwg & 7;
  const int xcd = orig & 7, loc = orig >> 3;
  const int swz = (xcd < rm ? xcd * (qd + 1) : rm * (qd + 1) + (xcd - rm) * qd) + loc;
  const int bn = swz % nbn, bm = swz / nbn;
  const int m0 = bm * 256, n0 = bn * 256;

  auto stage = [&](int slot, int unit, int kt) {
    const unsigned short* src = (unit < 2) ? A : B;
    const int row0 = (unit < 2) ? (m0 + unit * 128) : (n0 + (unit - 2) * 128);
    char* dst = (char*)lds[slot][unit];
    const int k0 = kt * 64;
#pragma unroll
    for (int j = 0; j < 2; ++j) {
      const int cs = (w * 2 + j) * 64 + l;
      const int r = cs >> 3, kc = (cs & 7) ^ (r & 7);
      llds16(src + (size_t)(row0 + r) * K + k0 + kc * 8, dst + (w * 2 + j) * 1024);
    }
  };
  auto rdA = [&](int slot, int rb, int ks) -> bf16x8 {
    const int row = rb * 16 + ln15;
    const int kc = (ks * 4 + hi) ^ (row & 7);
    return *(const bf16x8*)((const char*)lds[slot][wm] + row * 128 + kc * 16);
  };
  auto rdB = [&](int slot, int cb, int ks) -> bf16x8 {
    const int row = (wn & 1) * 64 + cb * 16 + ln15;
    const int kc = (ks * 4 + hi) ^ (row & 7);
    return *(const bf16x8*)((const char*)lds[slot][2 + (wn >> 1)] + row * 128 + kc * 16);
  };

#define PH_MID                                            \
  __builtin_amdgcn_s_barrier();                           \
  asm volatile("s_waitcnt lgkmcnt(0)" ::: "memory");      \
  __builtin_amdgcn_sched_barrier(0);                      \
  __builtin_amdgcn_s_setprio(1);
#define PH_END                                            \
  __builtin_amdgcn_s_setprio(0);                          \
  __builtin_amdgcn_s_barrier();

  f32x4 acc[8][4] = {};
  const int KT = K >> 6, NIT = KT >> 1;

  // prologue: tile0 (4 units) + B(1); drain tile0, keep B(1) in flight
  stage(0, 0, 0); stage(0, 1, 0); stage(0, 2, 0); stage(0, 3, 0);
  stage(1, 2, 1); stage(1, 3, 1);
  asm volatile("s_waitcnt vmcnt(4)" ::: "memory");
  __builtin_amdgcn_s_barrier();

  for (int it = 0; it < NIT; ++it) {
    const int t = 2 * it;
    const bool pre = (it < NIT - 1);
    bf16x8 a0[2][4], a1[2][4], b0[2][2], b1[2][2];

    // ---- phase 0: tile t (slot0), quadrant (r0-3, c0-1); stage A-top(t+1)
#pragma unroll
    for (int ks = 0; ks < 2; ++ks) {
#pragma unroll
      for (int r = 0; r < 4; ++r) a0[ks][r] = rdA(0, r, ks);
#pragma unroll
      for (int j = 0; j < 2; ++j) b0[ks][j] = rdB(0, j, ks);
    }
    stage(1, 0, t + 1);
    PH_MID
#pragma unroll
    for (int r = 0; r < 4; ++r)
#pragma unroll
      for (int j = 0; j < 2; ++j) {
        acc[r][j] = MFMA(a0[0][r], b0[0][j], acc[r][j]);
        acc[r][j] = MFMA(a0[1][r], b0[1][j], acc[r][j]);
      }
    PH_END

    // ---- phase 1: quadrant (r0-3, c2-3); stage A-bot(t+1)
#pragma unroll
    for (int ks = 0; ks < 2; ++ks)
#pragma unroll
      for (int j = 0; j < 2; ++j) b1[ks][j] = rdB(0, 2 + j, ks);
    stage(1, 1, t + 1);
    PH_MID
#pragma unroll
    for (int r = 0; r < 4; ++r)
#pragma unroll
      for (int j = 0; j < 2; ++j) {
        acc[r][2 + j] = MFMA(a0[0][r], b1[0][j], acc[r][2 + j]);
        acc[r][2 + j] = MFMA(a0[1][r], b1[1][j], acc[r][2 + j]);
      }
    PH_END

    // ---- phase 2: quadrant (r4-7, c0-1); stage B-top(t+2)
#pragma unroll
    for (int ks = 0; ks < 2; ++ks)
#pragma unroll
      for (int r = 0; r < 4; ++r) a1[ks][r] = rdA(0, 4 + r, ks);
    if (pre) stage(0, 2, t + 2);
    PH_MID
#pragma unroll
    for (int r = 0; r < 4; ++r)
#pragma unroll
      for (int j = 0; j < 2; ++j) {
        acc[4 + r][j] = MFMA(a1[0][r], b0[0][j], acc[4 + r][j]);
        acc[4 + r][j] = MFMA(a1[1][r], b0[1][j], acc[4 + r][j]);
      }
    PH_END

    // ---- phase 3: quadrant (r4-7, c2-3); stage B-bot(t+2); vmcnt(4)
    if (pre) stage(0, 3, t + 2);
    __builtin_amdgcn_s_barrier();
    __builtin_amdgcn_s_setprio(1);
#pragma unroll
    for (int r = 0; r < 4; ++r)
#pragma unroll
      for (int j = 0; j < 2; ++j) {
        acc[4 + r][2 + j] = MFMA(a1[0][r], b1[0][j], acc[4 + r][2 + j]);
        acc[4 + r][2 + j] = MFMA(a1[1][r], b1[1][j], acc[4 + r][2 + j]);
      }
    __builtin_amdgcn_s_setprio(0);
    if (pre) asm volatile("s_waitcnt vmcnt(4)" ::: "memory");
    else     asm volatile("s_waitcnt vmcnt(0)" ::: "memory");
    __builtin_amdgcn_s_barrier();

    // ---- phase 4: tile t+1 (slot1), quadrant (r0-3, c0-1); stage A-top(t+2)
#pragma unroll
    for (int ks = 0; ks < 2; ++ks) {
#pragma unroll
      for (int r = 0; r < 4; ++r) a0[ks][r] = rdA(1, r, ks);
#pragma unroll
      for (int j = 0; j < 2; ++j) b0[ks][j] = rdB(1, j, ks);
    }
    if (pre) stage(0, 0, t + 2);
    PH_MID
#pragma unroll
    for (int r = 0; r < 4; ++r)
#pragma unroll
      for (int j = 0; j < 2; ++j) {
        acc[r][j] = MFMA(a0[0][r], b0[0][j], acc[r][j]);
        acc[r][j] = MFMA(a0[1][r], b0[1][j], acc[r][j]);
      }
    PH_END

    // ---- phase 5: quadrant (r0-3, c2-3); stage A-bot(t+2)
#pragma unroll
    for (int ks = 0; ks < 2; ++ks)
#pragma unroll
      for (int j = 0; j < 2; ++j) b1[ks][j] = rdB(1, 2 + j, ks);
    if (pre) stage(0, 1, t + 2);
    PH_MID
#pragma unroll
    for (int r = 0; r < 4; ++r)
#pragma unroll
      for (int j = 0; j < 2; ++j) {
        acc[r][2 + j] = MFMA(a0[0][r], b1[0][j], acc[r][2 + j]);
        acc[r][2 + j] = MFMA(a0[1][r], b1[1][j], acc[r][2 + j]);
      }
    PH_END

    // ---- phase 6: quadrant (r4-7, c0-1); stage B-top(t+3)
#pragma unroll
    for (int ks = 0; ks < 2; ++ks)
#pragma unroll
      for (int r = 0; r < 4; ++r) a1[ks][r] = rdA(1, 4 + r, ks);
    if (pre) stage(1, 2, t + 3);
    PH_MID
#pragma unroll
    for (int r = 0; r < 4; ++r)
#pragma unroll
      for (int j = 0; j < 2; ++j) {
        acc[4 + r][j] = MFMA(a1[0][r], b0[0][j], acc[4 + r][j]);
        acc[4 + r][j] = MFMA(a1[1][r], b0[1][j], acc[4 + r][j]);
      }
    PH_END

    // ---- phase 7: quadrant (r4-7, c2-3); stage B-bot(t+3); vmcnt(4)
    if (pre) stage(1, 3, t + 3);
    __builtin_amdgcn_s_barrier();
    __builtin_amdgcn_s_setprio(1);
#pragma unroll
    for (int r = 0; r < 4; ++r)
#pragma unroll
      for (int j = 0; j < 2; ++j) {
        acc[4 + r][2 + j] = MFMA(a1[0][r], b1[0][j], acc[4 + r][2 + j]);
        acc[4 + r][2 + j] = MFMA(a1[1][r], b1[1][j], acc[4 + r][2 + j]);
      }
    __builtin_amdgcn_s_setprio(0);
    if (pre) {
      asm volatile("s_waitcnt vmcnt(4)" ::: "memory");
      __builtin_amdgcn_s_barrier();
    }
  }
#undef PH_MID
#undef PH_END

  // epilogue: C/D layout col=lane&15, row=(lane>>4)*4+reg
#pragma unroll
  for (int i = 0; i < 8; ++i) {
    const int rowb = m0 + wm * 128 + i * 16 + hi * 4;
#pragma unroll
    for (int j = 0; j < 4; ++j) {
      const int col = n0 + wn * 64 + j * 16 + ln15;
#pragma unroll
      for (int r = 0; r < 4; ++r) {
        float v = acc[i][j][r];
        if (col >= act_col0) v = tanhf(v + bias[col - act_col0]);
        const size_t off = (size_t)(rowb + r) * N + col;
        if (OUTF == 0) ((unsigned short*)Cout)[off] = f2b(v);
        else ((float*)Cout)[off] = v;
      }
    }
  }
}

// ---------- 128x128 m97-style GEMM (proven; used for o-projection) ----------
template <int OUTF>
__global__ __launch_bounds__(256, 2) void gemm_bt_kernel(
    const unsigned short* __restrict__ A, const unsigned short* __restrict__ B,
    void* __restrict__ Cout, int M, int N, int K, int act_col0,
    const float* __restrict__ bias) {
  __shared__ unsigned short As[128 * 32];
  __shared__ unsigned short Bs[128 * 32];
  const int tid = threadIdx.x;
  const int lane = tid & 63;
  const int w = tid >> 6;
  const int wr = w >> 1, wc = w & 1;
  const int ln15 = lane & 15, hi = lane >> 4;
  const int m0 = blockIdx.y * 128;
  const int n0 = blockIdx.x * 128;

  f32x4 acc[4][4] = {};
  const int nk = K >> 5;
  for (int kt = 0; kt < nk; ++kt) {
    const int kbase = kt * 32;
#pragma unroll
    for (int i = 0; i < 2; ++i) {
      int idx = i * 256 + tid;
      int row = idx >> 2, ch = idx & 3;
      int lb = (i * 256 + (tid >> 6) * 64) * 16;
      llds16(A + (size_t)(m0 + row) * K + kbase + ch * 8, (char*)As + lb);
      llds16(B + (size_t)(n0 + row) * K + kbase + ch * 8, (char*)Bs + lb);
    }
    __syncthreads();
    bf16x8 af[4], bf[4];
#pragma unroll
    for (int i = 0; i < 4; ++i) {
      af[i] = *(const bf16x8*)((const char*)As + (wr * 64 + i * 16 + ln15) * 64 + hi * 16);
      bf[i] = *(const bf16x8*)((const char*)Bs + (wc * 64 + i * 16 + ln15) * 64 + hi * 16);
    }
#pragma unroll
    for (int i = 0; i < 4; ++i)
#pragma unroll
      for (int j = 0; j < 4; ++j)
        acc[i][j] = MFMA(af[i], bf[j], acc[i][j]);
    __syncthreads();
  }
#pragma unroll
  for (int i = 0; i < 4; ++i) {
    int rowb = m0 + wr * 64 + i * 16 + hi * 4;
#pragma unroll
    for (int j = 0; j < 4; ++j) {
      int col = n0 + wc * 64 + j * 16 + ln15;
#pragma unroll
      for (int r = 0; r < 4; ++r) {
        float v = acc[i][j][r];
        if (col >= act_col0) v = tanhf(v + bias[col - act_col0]);
        size_t off = (size_t)(rowb + r) * N + col;
        if (OUTF == 0) ((unsigned short*)Cout)[off] = f2b(v);
        else ((float*)Cout)[off] = v;
      }
    }
  }
}

// ---------- sensor layer 2: lc = sigmoid(h1 @ w2.T + b2) ----------
__global__ __launch_bounds__(256) void sensor2_kernel(
    const unsigned short* __restrict__ QKVH, const float* __restrict__ w2,
    const float* __restrict__ b2, float* __restrict__ LC) {
  const int tid = threadIdx.x;
  const int h = tid & 15, r = tid >> 4;
  const int m = blockIdx.x * 16 + r;
  const unsigned short* hrow = QKVH + (size_t)m * 3328 + 3072;
  const float* wrow = w2 + h * 256;
  float acc = 0.0f;
  for (int d = 0; d < 256; d += 8) {
    uint4 hv = *(const uint4*)(hrow + d);
    float4 wa = *(const float4*)(wrow + d);
    float4 wb = *(const float4*)(wrow + d + 4);
    acc = fmaf(blo(hv.x), wa.x, acc); acc = fmaf(bhi(hv.x), wa.y, acc);
    acc = fmaf(blo(hv.y), wa.z, acc); acc = fmaf(bhi(hv.y), wa.w, acc);
    acc = fmaf(blo(hv.z), wb.x, acc); acc = fmaf(bhi(hv.z), wb.y, acc);
    acc = fmaf(blo(hv.w), wb.z, acc); acc = fmaf(bhi(hv.w), wb.w, acc);
  }
  LC[(size_t)m * 16 + h] = sigf(acc + b2[h]);
}

// ---------- scan pass A ----------
__global__ __launch_bounds__(256) void scan_passA_kernel(
    const unsigned short* __restrict__ QKVH, const float* __restrict__ LC,
    const float* __restrict__ decay, float* __restrict__ MS, float* __restrict__ P) {
  __shared__ unsigned short kL[4096], vL[4096];
  __shared__ float lamL[4096];
  __shared__ float sigL[64], lcL[64];
  const int tid = threadIdx.x;
  const int c = blockIdx.x, h = blockIdx.y, b = blockIdx.z;
  const int t0 = c * 64;
  const int eg = tid & 3, fo = tid >> 2, e0 = eg * 16;

#pragma unroll
  for (int i = 0; i < 2; ++i) {
    int idx = i * 256 + tid;
    int row = idx >> 3, ch = idx & 7;
    size_t g = (size_t)(b * 2048 + t0 + row) * 3328 + h * 64 + ch * 8;
    int lb = (i * 256 + (tid >> 6) * 64) * 16;
    llds16(QKVH + g + 1024, (char*)kL + lb);
    llds16(QKVH + g + 2048, (char*)vL + lb);
  }
  if (tid < 64) sigL[tid] = sigf(decay[h * 64 + tid]);
  else if (tid < 128) lcL[tid - 64] = LC[(size_t)(b * 2048 + t0 + tid - 64) * 16 + h];
  __syncthreads();
#pragma unroll
  for (int i = 0; i < 16; ++i) {
    int idx = i * 256 + tid;
    lamL[idx] = fminf(sigL[idx & 63] * (1.0f + 0.2f * lcL[idx >> 6]), 0.9995f);
  }
  __syncthreads();

  float S[16], Pr[16];
#pragma unroll
  for (int i = 0; i < 16; ++i) { S[i] = 0.0f; Pr[i] = 1.0f; }

  for (int t = 0; t < 64; ++t) {
    float lam[16], kk[16];
#pragma unroll
    for (int j = 0; j < 4; ++j) {
      f32x4 l4 = *(const f32x4*)&lamL[t * 64 + e0 + j * 4];
      lam[j * 4 + 0] = l4[0]; lam[j * 4 + 1] = l4[1];
      lam[j * 4 + 2] = l4[2]; lam[j * 4 + 3] = l4[3];
    }
    uint4 k0 = *(const uint4*)&kL[t * 64 + e0];
    uint4 k1 = *(const uint4*)&kL[t * 64 + e0 + 8];
    unpack8(k0, kk); unpack8(k1, kk + 8);
    float vf = blo((unsigned)vL[t * 64 + fo]);
#pragma unroll
    for (int i = 0; i < 16; ++i) {
      S[i] = fmaf(S[i], lam[i], kk[i] * vf);
      Pr[i] *= lam[i];
    }
  }
  size_t slot = (size_t)((b * 16 + h) * 32 + c);
  float* Mp = MS + slot * 4096;
#pragma unroll
  for (int i = 0; i < 16; ++i) Mp[(e0 + i) * 64 + fo] = S[i];
  if (fo == 0) {
#pragma unroll
    for (int i = 0; i < 16; ++i) P[slot * 64 + e0 + i] = Pr[i];
  }
}

// ---------- scan pass B: chunk-state composition, elementwise-parallel ----------
__global__ __launch_bounds__(256) void scan_passB_kernel(
    float* __restrict__ MS, const float* __restrict__ P) {
  const int bh = blockIdx.y;
  const int ef = blockIdx.x * 256 + threadIdx.x;
  const int e = ef >> 6;
  const size_t base = (size_t)bh * 32;
  float S = 0.0f;
  for (int c = 0; c < 32; ++c) {
    float* Mp = MS + (base + c) * 4096 + ef;
    const float p = P[(base + c) * 64 + e];
    const float m = *Mp;
    *Mp = S;
    S = fmaf(p, S, m);
  }
}

// ---------- scan pass C ----------
__global__ __launch_bounds__(256) void scan_passC_kernel(
    const unsigned short* __restrict__ QKVH, const float* __restrict__ LC,
    const float* __restrict__ decay, const float* __restrict__ MS,
    unsigned short* __restrict__ Y) {
  __shared__ unsigned short qL[4096], kL[4096], vL[4096];
  __shared__ float lamL[4096];
  __shared__ float sigL[64], lcL[64];
  const int tid = threadIdx.x;
  const int c = blockIdx.x, h = blockIdx.y, b = blockIdx.z;
  const int t0 = c * 64;
  const int eg = tid & 3, fo = tid >> 2, e0 = eg * 16;

#pragma unroll
  for (int i = 0; i < 2; ++i) {
    int idx = i * 256 + tid;
    int row = idx >> 3, ch = idx & 7;
    size_t g = (size_t)(b * 2048 + t0 + row) * 3328 + h * 64 + ch * 8;
    int lb = (i * 256 + (tid >> 6) * 64) * 16;
    llds16(QKVH + g,        (char*)qL + lb);
    llds16(QKVH + g + 1024, (char*)kL + lb);
    llds16(QKVH + g + 2048, (char*)vL + lb);
  }
  if (tid < 64) sigL[tid] = sigf(decay[h * 64 + tid]);
  else if (tid < 128) lcL[tid - 64] = LC[(size_t)(b * 2048 + t0 + tid - 64) * 16 + h];
  __syncthreads();
#pragma unroll
  for (int i = 0; i < 16; ++i) {
    int idx = i * 256 + tid;
    lamL[idx] = fminf(sigL[idx & 63] * (1.0f + 0.2f * lcL[idx >> 6]), 0.9995f);
  }
  const float* Sp = MS + ((size_t)((b * 16 + h) * 32 + c)) * 4096;
  float S[16];
#pragma unroll
  for (int i = 0; i < 16; ++i) S[i] = Sp[(e0 + i) * 64 + fo];
  __syncthreads();

  unsigned short* Yp = Y + (size_t)(b * 2048 + t0) * 1024 + h * 64 + fo;
  for (int t = 0; t < 64; ++t) {
    float lam[16], kk[16], qq[16];
#pragma unroll
    for (int j = 0; j < 4; ++j) {
      f32x4 l4 = *(const f32x4*)&lamL[t * 64 + e0 + j * 4];
      lam[j * 4 + 0] = l4[0]; lam[j * 4 + 1] = l4[1];
      lam[j * 4 + 2] = l4[2]; lam[j * 4 + 3] = l4[3];
    }
    uint4 k0 = *(const uint4*)&kL[t * 64 + e0];
    uint4 k1 = *(const uint4*)&kL[t * 64 + e0 + 8];
    unpack8(k0, kk); unpack8(k1, kk + 8);
    uint4 q0 = *(const uint4*)&qL[t * 64 + e0];
    uint4 q1 = *(const uint4*)&qL[t * 64 + e0 + 8];
    unpack8(q0, qq); unpack8(q1, qq + 8);
    float vf = blo((unsigned)vL[t * 64 + fo]);
    float acc = 0.0f;
#pragma unroll
    for (int i = 0; i < 16; ++i) {
      S[i] = fmaf(S[i], lam[i], kk[i] * vf);
      acc = fmaf(qq[i], S[i], acc);
    }
    acc += __shfl_xor(acc, 1);
    acc += __shfl_xor(acc, 2);
    if (eg == 0) Yp[(size_t)t * 1024] = f2b(acc);
  }
}

// ---------- host launch ----------
extern "C" void kernel_launch(void* const* d_in, const int* in_sizes, int n_in,
                              void* d_out, int out_size, void* d_ws, size_t ws_size,
                              hipStream_t stream) {
  (void)in_sizes; (void)n_in; (void)out_size; (void)ws_size;
  const float* x     = (const float*)d_in[0];
  const float* q_w   = (const float*)d_in[1];
  const float* k_w   = (const float*)d_in[2];
  const float* v_w   = (const float*)d_in[3];
  const float* o_w   = (const float*)d_in[4];
  const float* cs_w1 = (const float*)d_in[5];
  const float* cs_b1 = (const float*)d_in[6];
  const float* cs_w2 = (const float*)d_in[7];
  const float* cs_b2 = (const float*)d_in[8];
  const float* decay = (const float*)d_in[9];
  float* out = (float*)d_out;

  char* ws = (char*)d_ws;
  unsigned short* XB   = (unsigned short*)(ws);
  unsigned short* WCAT = (unsigned short*)(ws + 16777216);
  unsigned short* OWB  = (unsigned short*)(ws + 23592960);
  unsigned short* QKVH = (unsigned short*)(ws + 25690112);
  float*          LCb  = (float*)(ws + 80216064);
  float*          MS   = (float*)(ws + 80740352);
  float*          Pb   = (float*)(ws + 114294784);
  unsigned short* YB   = (unsigned short*)(ws + 114819072);

  // 1) bf16 conversions (single launch)
  cvt_all_kernel<<<12544, 256, 0, stream>>>(x, q_w, k_w, v_w, cs_w1, o_w,
                                            XB, WCAT, OWB);

  // 2) fused q|k|v|h1 GEMM: [8192x1024] @ [3328x1024]^T, tanh+bias on cols >=3072
  gemm8p_kernel<0><<<416, 512, 0, stream>>>(XB, WCAT, QKVH, 8192, 3328,
                                            1024, 3072, cs_b1, 13);
  // 3) sensor layer 2 -> lc
  sensor2_kernel<<<512, 256, 0, stream>>>(QKVH, cs_w2, cs_b2, LCb);

  // 4) chunked scan (L=64, C=32)
  scan_passA_kernel<<<dim3(32, 16, 4), 256, 0, stream>>>(QKVH, LCb, decay, MS, Pb);
  scan_passB_kernel<<<dim3(16, 64), 256, 0, stream>>>(MS, Pb);
  scan_passC_kernel<<<dim3(32, 16, 4), 256, 0, stream>>>(QKVH, LCb, decay, MS, YB);

  // 5) o-projection: [8192x1024] @ [1024x1024]^T -> fp32 out (128^2 kernel, 512 blocks)
  gemm_bt_kernel<1><<<dim3(8, 64), 256, 0, stream>>>(YB, OWB, out, 8192, 1024,
                                                     1024, 1 << 30, nullptr);
}

// Round 4
// 263.487 us; speedup vs baseline: 1.1890x; 1.1083x over previous
//
#include <hip/hip_runtime.h>

#define DEV __device__ __forceinline__
#define MFMA(a, b, c) __builtin_amdgcn_mfma_f32_16x16x32_bf16(a, b, c, 0, 0, 0)

typedef __bf16 bf16x8 __attribute__((ext_vector_type(8)));
typedef float f32x4 __attribute__((ext_vector_type(4)));

// ---------- helpers ----------
DEV float blo(unsigned u) { return __builtin_bit_cast(float, u << 16); }
DEV float bhi(unsigned u) { return __builtin_bit_cast(float, u & 0xFFFF0000u); }
DEV unsigned short f2b(float f) {
  unsigned u = __builtin_bit_cast(unsigned, f);
  return (unsigned short)((u + 0x7FFFu + ((u >> 16) & 1u)) >> 16);
}
DEV float sigf(float x) { return 1.0f / (1.0f + expf(-x)); }

DEV void llds16(const void* g, void* l) {
  __builtin_amdgcn_global_load_lds(
      (__attribute__((address_space(1))) void*)(void*)g,
      (__attribute__((address_space(3))) void*)l, 16, 0, 0);
}

DEV void unpack8(uint4 u, float* d) {
  d[0] = blo(u.x); d[1] = bhi(u.x); d[2] = blo(u.y); d[3] = bhi(u.y);
  d[4] = blo(u.z); d[5] = bhi(u.z); d[6] = blo(u.w); d[7] = bhi(u.w);
}

// ---------- fused fp32 -> bf16 conversion (all 6 tensors, 1 launch) ----------
__global__ __launch_bounds__(256) void cvt_all_kernel(
    const float* __restrict__ x, const float* __restrict__ qw,
    const float* __restrict__ kw, const float* __restrict__ vw,
    const float* __restrict__ cw1, const float* __restrict__ ow,
    unsigned short* __restrict__ XB, unsigned short* __restrict__ WCAT,
    unsigned short* __restrict__ OWB) {
  const int i = blockIdx.x * 256 + threadIdx.x;
  const float* s;
  unsigned short* d;
  if (i < 2097152)      { s = x   + (size_t)i * 4;                 d = XB + (size_t)i * 4; }
  else if (i < 2359296) { size_t j = i - 2097152; s = qw  + j * 4; d = WCAT + j * 4; }
  else if (i < 2621440) { size_t j = i - 2359296; s = kw  + j * 4; d = WCAT + 1048576 + j * 4; }
  else if (i < 2883584) { size_t j = i - 2621440; s = vw  + j * 4; d = WCAT + 2097152 + j * 4; }
  else if (i < 2949120) { size_t j = i - 2883584; s = cw1 + j * 4; d = WCAT + 3145728 + j * 4; }
  else if (i < 3211264) { size_t j = i - 2949120; s = ow  + j * 4; d = OWB + j * 4; }
  else return;
  float4 f = *(const float4*)s;
  ushort4 o;
  o.x = f2b(f.x); o.y = f2b(f.y); o.z = f2b(f.z); o.w = f2b(f.w);
  *(ushort4*)d = o;
}

// ---------- 128x128 m97-structure GEMM, BK=64, conflict-free XOR swizzle ----------
// C[m][n] = sum_k A[m][k]*B[n][k], both row-major bf16. Single-buffered
// 2-barrier loop (proven structure); BK=64 halves barrier count vs BK=32.
// LDS rows are 128B = 8 x 16B slots; slot ^= (row&7) on BOTH the global
// source (stage) and the ds_read -> 0 bank conflicts (verified in r2/r3 8p).
// XCD-bijective block swizzle, bn-fast order for L2 locality.
// Columns >= act_col0 get v = tanh(v + bias[col-act_col0]).
template <int OUTF>  // 0 = bf16 out, 1 = fp32 out
__global__ __launch_bounds__(256, 2) void gemm_bk64_kernel(
    const unsigned short* __restrict__ A, const unsigned short* __restrict__ B,
    void* __restrict__ Cout, int M, int N, int K, int act_col0,
    const float* __restrict__ bias, int nbn) {
  __shared__ char As[16384];  // 128 rows x 64 k (bf16), swizzled 16B slots
  __shared__ char Bs[16384];
  const int tid = threadIdx.x;
  const int lane = tid & 63;
  const int w = tid >> 6;            // 0..3
  const int wr = w >> 1, wc = w & 1;
  const int ln15 = lane & 15, hi = lane >> 4;

  // bijective XCD swizzle (m204), bn-fast for A-panel L2 reuse
  const int nwg = gridDim.x, orig = blockIdx.x;
  const int qd = nwg >> 3, rm = nwg & 7;
  const int xcd = orig & 7, loc = orig >> 3;
  const int swz = (xcd < rm ? xcd * (qd + 1) : rm * (qd + 1) + (xcd - rm) * qd) + loc;
  const int bn = swz % nbn, bm = swz / nbn;
  const int m0 = bm * 128, n0 = bn * 128;

  auto stage = [&](const unsigned short* src, int row0, int k0, char* dst) {
#pragma unroll
    for (int j = 0; j < 4; ++j) {
      const int slot = j * 256 + tid;          // 0..1023 16B-slots
      const int rr = slot >> 3;                // row 0..127
      const int kc = (slot & 7) ^ (rr & 7);    // inverse swizzle on source
      llds16(src + (size_t)(row0 + rr) * K + k0 + kc * 8, dst + slot * 16);
    }
  };
  auto rd = [&](const char* unit, int row, int ks) -> bf16x8 {
    const int kc = (ks * 4 + hi) ^ (row & 7);
    return *(const bf16x8*)(unit + row * 128 + kc * 16);
  };

  f32x4 acc[4][4] = {};
  const int nk = K >> 6;
  for (int kt = 0; kt < nk; ++kt) {
    stage(A, m0, kt * 64, As);
    stage(B, n0, kt * 64, Bs);
    __syncthreads();
    bf16x8 af[2][4], bf[2][4];
#pragma unroll
    for (int ks = 0; ks < 2; ++ks)
#pragma unroll
      for (int i = 0; i < 4; ++i) {
        af[ks][i] = rd(As, wr * 64 + i * 16 + ln15, ks);
        bf[ks][i] = rd(Bs, wc * 64 + i * 16 + ln15, ks);
      }
#pragma unroll
    for (int i = 0; i < 4; ++i)
#pragma unroll
      for (int j = 0; j < 4; ++j) {
        acc[i][j] = MFMA(af[0][i], bf[0][j], acc[i][j]);
        acc[i][j] = MFMA(af[1][i], bf[1][j], acc[i][j]);
      }
    __syncthreads();
  }
  // epilogue: C/D layout col=lane&15, row=(lane>>4)*4+reg
#pragma unroll
  for (int i = 0; i < 4; ++i) {
    const int rowb = m0 + wr * 64 + i * 16 + hi * 4;
#pragma unroll
    for (int j = 0; j < 4; ++j) {
      const int col = n0 + wc * 64 + j * 16 + ln15;
#pragma unroll
      for (int r = 0; r < 4; ++r) {
        float v = acc[i][j][r];
        if (col >= act_col0) v = tanhf(v + bias[col - act_col0]);
        const size_t off = (size_t)(rowb + r) * N + col;
        if (OUTF == 0) ((unsigned short*)Cout)[off] = f2b(v);
        else ((float*)Cout)[off] = v;
      }
    }
  }
}

// ---------- sensor layer 2: lc = sigmoid(h1 @ w2.T + b2) ----------
__global__ __launch_bounds__(256) void sensor2_kernel(
    const unsigned short* __restrict__ QKVH, const float* __restrict__ w2,
    const float* __restrict__ b2, float* __restrict__ LC) {
  const int tid = threadIdx.x;
  const int h = tid & 15, r = tid >> 4;
  const int m = blockIdx.x * 16 + r;
  const unsigned short* hrow = QKVH + (size_t)m * 3328 + 3072;
  const float* wrow = w2 + h * 256;
  float acc = 0.0f;
  for (int d = 0; d < 256; d += 8) {
    uint4 hv = *(const uint4*)(hrow + d);
    float4 wa = *(const float4*)(wrow + d);
    float4 wb = *(const float4*)(wrow + d + 4);
    acc = fmaf(blo(hv.x), wa.x, acc); acc = fmaf(bhi(hv.x), wa.y, acc);
    acc = fmaf(blo(hv.y), wa.z, acc); acc = fmaf(bhi(hv.y), wa.w, acc);
    acc = fmaf(blo(hv.z), wb.x, acc); acc = fmaf(bhi(hv.z), wb.y, acc);
    acc = fmaf(blo(hv.w), wb.z, acc); acc = fmaf(bhi(hv.w), wb.w, acc);
  }
  LC[(size_t)m * 16 + h] = sigf(acc + b2[h]);
}

// ---------- scan pass A: per-chunk scan from zero -> M (fp32), P = prod(lam) ----------
__global__ __launch_bounds__(256) void scan_passA_kernel(
    const unsigned short* __restrict__ QKVH, const float* __restrict__ LC,
    const float* __restrict__ decay, float* __restrict__ MS, float* __restrict__ P) {
  __shared__ unsigned short kL[4096], vL[4096];
  __shared__ float lamL[4096];
  __shared__ float sigL[64], lcL[64];
  const int tid = threadIdx.x;
  const int c = blockIdx.x, h = blockIdx.y, b = blockIdx.z;
  const int t0 = c * 64;
  const int eg = tid & 3, fo = tid >> 2, e0 = eg * 16;

#pragma unroll
  for (int i = 0; i < 2; ++i) {
    int idx = i * 256 + tid;
    int row = idx >> 3, ch = idx & 7;
    size_t g = (size_t)(b * 2048 + t0 + row) * 3328 + h * 64 + ch * 8;
    int lb = (i * 256 + (tid >> 6) * 64) * 16;
    llds16(QKVH + g + 1024, (char*)kL + lb);
    llds16(QKVH + g + 2048, (char*)vL + lb);
  }
  if (tid < 64) sigL[tid] = sigf(decay[h * 64 + tid]);
  else if (tid < 128) lcL[tid - 64] = LC[(size_t)(b * 2048 + t0 + tid - 64) * 16 + h];
  __syncthreads();
#pragma unroll
  for (int i = 0; i < 16; ++i) {
    int idx = i * 256 + tid;
    lamL[idx] = fminf(sigL[idx & 63] * (1.0f + 0.2f * lcL[idx >> 6]), 0.9995f);
  }
  __syncthreads();

  float S[16], Pr[16];
#pragma unroll
  for (int i = 0; i < 16; ++i) { S[i] = 0.0f; Pr[i] = 1.0f; }

  for (int t = 0; t < 64; ++t) {
    float lam[16], kk[16];
#pragma unroll
    for (int j = 0; j < 4; ++j) {
      f32x4 l4 = *(const f32x4*)&lamL[t * 64 + e0 + j * 4];
      lam[j * 4 + 0] = l4[0]; lam[j * 4 + 1] = l4[1];
      lam[j * 4 + 2] = l4[2]; lam[j * 4 + 3] = l4[3];
    }
    uint4 k0 = *(const uint4*)&kL[t * 64 + e0];
    uint4 k1 = *(const uint4*)&kL[t * 64 + e0 + 8];
    unpack8(k0, kk); unpack8(k1, kk + 8);
    float vf = blo((unsigned)vL[t * 64 + fo]);
#pragma unroll
    for (int i = 0; i < 16; ++i) {
      S[i] = fmaf(S[i], lam[i], kk[i] * vf);
      Pr[i] *= lam[i];
    }
  }
  size_t slot = (size_t)((b * 16 + h) * 32 + c);
  float* Mp = MS + slot * 4096;
#pragma unroll
  for (int i = 0; i < 16; ++i) Mp[(e0 + i) * 64 + fo] = S[i];
  if (fo == 0) {
#pragma unroll
    for (int i = 0; i < 16; ++i) P[slot * 64 + e0 + i] = Pr[i];
  }
}

// ---------- scan pass B: chunk-state composition, elementwise-parallel ----------
__global__ __launch_bounds__(256) void scan_passB_kernel(
    float* __restrict__ MS, const float* __restrict__ P) {
  const int bh = blockIdx.y;
  const int ef = blockIdx.x * 256 + threadIdx.x;
  const int e = ef >> 6;
  const size_t base = (size_t)bh * 32;
  float S = 0.0f;
  for (int c = 0; c < 32; ++c) {
    float* Mp = MS + (base + c) * 4096 + ef;
    const float p = P[(base + c) * 64 + e];
    const float m = *Mp;
    *Mp = S;
    S = fmaf(p, S, m);
  }
}

// ---------- scan pass C: re-run chunk from true S_in, emit y ----------
__global__ __launch_bounds__(256) void scan_passC_kernel(
    const unsigned short* __restrict__ QKVH, const float* __restrict__ LC,
    const float* __restrict__ decay, const float* __restrict__ MS,
    unsigned short* __restrict__ Y) {
  __shared__ unsigned short qL[4096], kL[4096], vL[4096];
  __shared__ float lamL[4096];
  __shared__ float sigL[64], lcL[64];
  const int tid = threadIdx.x;
  const int c = blockIdx.x, h = blockIdx.y, b = blockIdx.z;
  const int t0 = c * 64;
  const int eg = tid & 3, fo = tid >> 2, e0 = eg * 16;

#pragma unroll
  for (int i = 0; i < 2; ++i) {
    int idx = i * 256 + tid;
    int row = idx >> 3, ch = idx & 7;
    size_t g = (size_t)(b * 2048 + t0 + row) * 3328 + h * 64 + ch * 8;
    int lb = (i * 256 + (tid >> 6) * 64) * 16;
    llds16(QKVH + g,        (char*)qL + lb);
    llds16(QKVH + g + 1024, (char*)kL + lb);
    llds16(QKVH + g + 2048, (char*)vL + lb);
  }
  if (tid < 64) sigL[tid] = sigf(decay[h * 64 + tid]);
  else if (tid < 128) lcL[tid - 64] = LC[(size_t)(b * 2048 + t0 + tid - 64) * 16 + h];
  __syncthreads();
#pragma unroll
  for (int i = 0; i < 16; ++i) {
    int idx = i * 256 + tid;
    lamL[idx] = fminf(sigL[idx & 63] * (1.0f + 0.2f * lcL[idx >> 6]), 0.9995f);
  }
  const float* Sp = MS + ((size_t)((b * 16 + h) * 32 + c)) * 4096;
  float S[16];
#pragma unroll
  for (int i = 0; i < 16; ++i) S[i] = Sp[(e0 + i) * 64 + fo];
  __syncthreads();

  unsigned short* Yp = Y + (size_t)(b * 2048 + t0) * 1024 + h * 64 + fo;
  for (int t = 0; t < 64; ++t) {
    float lam[16], kk[16], qq[16];
#pragma unroll
    for (int j = 0; j < 4; ++j) {
      f32x4 l4 = *(const f32x4*)&lamL[t * 64 + e0 + j * 4];
      lam[j * 4 + 0] = l4[0]; lam[j * 4 + 1] = l4[1];
      lam[j * 4 + 2] = l4[2]; lam[j * 4 + 3] = l4[3];
    }
    uint4 k0 = *(const uint4*)&kL[t * 64 + e0];
    uint4 k1 = *(const uint4*)&kL[t * 64 + e0 + 8];
    unpack8(k0, kk); unpack8(k1, kk + 8);
    uint4 q0 = *(const uint4*)&qL[t * 64 + e0];
    uint4 q1 = *(const uint4*)&qL[t * 64 + e0 + 8];
    unpack8(q0, qq); unpack8(q1, qq + 8);
    float vf = blo((unsigned)vL[t * 64 + fo]);
    float acc = 0.0f;
#pragma unroll
    for (int i = 0; i < 16; ++i) {
      S[i] = fmaf(S[i], lam[i], kk[i] * vf);
      acc = fmaf(qq[i], S[i], acc);
    }
    acc += __shfl_xor(acc, 1);
    acc += __shfl_xor(acc, 2);
    if (eg == 0) Yp[(size_t)t * 1024] = f2b(acc);
  }
}

// ---------- host launch ----------
extern "C" void kernel_launch(void* const* d_in, const int* in_sizes, int n_in,
                              void* d_out, int out_size, void* d_ws, size_t ws_size,
                              hipStream_t stream) {
  (void)in_sizes; (void)n_in; (void)out_size; (void)ws_size;
  const float* x     = (const float*)d_in[0];
  const float* q_w   = (const float*)d_in[1];
  const float* k_w   = (const float*)d_in[2];
  const float* v_w   = (const float*)d_in[3];
  const float* o_w   = (const float*)d_in[4];
  const float* cs_w1 = (const float*)d_in[5];
  const float* cs_b1 = (const float*)d_in[6];
  const float* cs_w2 = (const float*)d_in[7];
  const float* cs_b2 = (const float*)d_in[8];
  const float* decay = (const float*)d_in[9];
  float* out = (float*)d_out;

  char* ws = (char*)d_ws;
  unsigned short* XB   = (unsigned short*)(ws);
  unsigned short* WCAT = (unsigned short*)(ws + 16777216);
  unsigned short* OWB  = (unsigned short*)(ws + 23592960);
  unsigned short* QKVH = (unsigned short*)(ws + 25690112);
  float*          LCb  = (float*)(ws + 80216064);
  float*          MS   = (float*)(ws + 80740352);
  float*          Pb   = (float*)(ws + 114294784);
  unsigned short* YB   = (unsigned short*)(ws + 114819072);

  // 1) bf16 conversions (single launch)
  cvt_all_kernel<<<12544, 256, 0, stream>>>(x, q_w, k_w, v_w, cs_w1, o_w,
                                            XB, WCAT, OWB);

  // 2) fused q|k|v|h1 GEMM: [8192x1024] @ [3328x1024]^T, tanh+bias on cols >=3072
  gemm_bk64_kernel<0><<<1664, 256, 0, stream>>>(XB, WCAT, QKVH, 8192, 3328,
                                                1024, 3072, cs_b1, 26);
  // 3) sensor layer 2 -> lc
  sensor2_kernel<<<512, 256, 0, stream>>>(QKVH, cs_w2, cs_b2, LCb);

  // 4) chunked scan (L=64, C=32)
  scan_passA_kernel<<<dim3(32, 16, 4), 256, 0, stream>>>(QKVH, LCb, decay, MS, Pb);
  scan_passB_kernel<<<dim3(16, 64), 256, 0, stream>>>(MS, Pb);
  scan_passC_kernel<<<dim3(32, 16, 4), 256, 0, stream>>>(QKVH, LCb, decay, MS, YB);

  // 5) o-projection: [8192x1024] @ [1024x1024]^T -> fp32 out
  gemm_bk64_kernel<1><<<512, 256, 0, stream>>>(YB, OWB, out, 8192, 1024,
                                               1024, 1 << 30, nullptr, 8);
}

// Round 5
// 174.531 us; speedup vs baseline: 1.7950x; 1.5097x over previous
//
#include <hip/hip_runtime.h>

#define DEV __device__ __forceinline__
#define MFMA(a, b, c) __builtin_amdgcn_mfma_f32_16x16x32_bf16(a, b, c, 0, 0, 0)

typedef __bf16 bf16x8 __attribute__((ext_vector_type(8)));
typedef float f32x4 __attribute__((ext_vector_type(4)));
typedef unsigned short u16x8 __attribute__((ext_vector_type(8)));

// ---------- helpers ----------
DEV float blo(unsigned u) { return __builtin_bit_cast(float, u << 16); }
DEV float bhi(unsigned u) { return __builtin_bit_cast(float, u & 0xFFFF0000u); }
DEV unsigned short f2b(float f) {
  unsigned u = __builtin_bit_cast(unsigned, f);
  return (unsigned short)((u + 0x7FFFu + ((u >> 16) & 1u)) >> 16);
}
DEV float sigf(float x) { return 1.0f / (1.0f + expf(-x)); }

DEV void llds16(const void* g, void* l) {
  __builtin_amdgcn_global_load_lds(
      (__attribute__((address_space(1))) void*)(void*)g,
      (__attribute__((address_space(3))) void*)l, 16, 0, 0);
}

// ---------- fused fp32 -> bf16 conversion (all 6 tensors, 1 launch) ----------
__global__ __launch_bounds__(256) void cvt_all_kernel(
    const float* __restrict__ x, const float* __restrict__ qw,
    const float* __restrict__ kw, const float* __restrict__ vw,
    const float* __restrict__ cw1, const float* __restrict__ ow,
    unsigned short* __restrict__ XB, unsigned short* __restrict__ WCAT,
    unsigned short* __restrict__ OWB) {
  const int i = blockIdx.x * 256 + threadIdx.x;
  const float* s;
  unsigned short* d;
  if (i < 2097152)      { s = x   + (size_t)i * 4;                 d = XB + (size_t)i * 4; }
  else if (i < 2359296) { size_t j = i - 2097152; s = qw  + j * 4; d = WCAT + j * 4; }
  else if (i < 2621440) { size_t j = i - 2359296; s = kw  + j * 4; d = WCAT + 1048576 + j * 4; }
  else if (i < 2883584) { size_t j = i - 2621440; s = vw  + j * 4; d = WCAT + 2097152 + j * 4; }
  else if (i < 2949120) { size_t j = i - 2883584; s = cw1 + j * 4; d = WCAT + 3145728 + j * 4; }
  else if (i < 3211264) { size_t j = i - 2949120; s = ow  + j * 4; d = OWB + j * 4; }
  else return;
  float4 f = *(const float4*)s;
  ushort4 o;
  o.x = f2b(f.x); o.y = f2b(f.y); o.z = f2b(f.z); o.w = f2b(f.w);
  *(ushort4*)d = o;
}

// ---------- 128x128 GEMM, BK=64, conflict-free XOR swizzle (proven r4) ----------
template <int OUTF>  // 0 = bf16 out, 1 = fp32 out
__global__ __launch_bounds__(256, 2) void gemm_bk64_kernel(
    const unsigned short* __restrict__ A, const unsigned short* __restrict__ B,
    void* __restrict__ Cout, int M, int N, int K, int act_col0,
    const float* __restrict__ bias, int nbn) {
  __shared__ char As[16384];
  __shared__ char Bs[16384];
  const int tid = threadIdx.x;
  const int lane = tid & 63;
  const int w = tid >> 6;
  const int wr = w >> 1, wc = w & 1;
  const int ln15 = lane & 15, hi = lane >> 4;

  const int nwg = gridDim.x, orig = blockIdx.x;
  const int qd = nwg >> 3, rm = nwg & 7;
  const int xcd = orig & 7, loc = orig >> 3;
  const int swz = (xcd < rm ? xcd * (qd + 1) : rm * (qd + 1) + (xcd - rm) * qd) + loc;
  const int bn = swz % nbn, bm = swz / nbn;
  const int m0 = bm * 128, n0 = bn * 128;

  auto stage = [&](const unsigned short* src, int row0, int k0, char* dst) {
#pragma unroll
    for (int j = 0; j < 4; ++j) {
      const int slot = j * 256 + tid;
      const int rr = slot >> 3;
      const int kc = (slot & 7) ^ (rr & 7);
      llds16(src + (size_t)(row0 + rr) * K + k0 + kc * 8, dst + slot * 16);
    }
  };
  auto rd = [&](const char* unit, int row, int ks) -> bf16x8 {
    const int kc = (ks * 4 + hi) ^ (row & 7);
    return *(const bf16x8*)(unit + row * 128 + kc * 16);
  };

  f32x4 acc[4][4] = {};
  const int nk = K >> 6;
  for (int kt = 0; kt < nk; ++kt) {
    stage(A, m0, kt * 64, As);
    stage(B, n0, kt * 64, Bs);
    __syncthreads();
    bf16x8 af[2][4], bf[2][4];
#pragma unroll
    for (int ks = 0; ks < 2; ++ks)
#pragma unroll
      for (int i = 0; i < 4; ++i) {
        af[ks][i] = rd(As, wr * 64 + i * 16 + ln15, ks);
        bf[ks][i] = rd(Bs, wc * 64 + i * 16 + ln15, ks);
      }
#pragma unroll
    for (int i = 0; i < 4; ++i)
#pragma unroll
      for (int j = 0; j < 4; ++j) {
        acc[i][j] = MFMA(af[0][i], bf[0][j], acc[i][j]);
        acc[i][j] = MFMA(af[1][i], bf[1][j], acc[i][j]);
      }
    __syncthreads();
  }
#pragma unroll
  for (int i = 0; i < 4; ++i) {
    const int rowb = m0 + wr * 64 + i * 16 + hi * 4;
#pragma unroll
    for (int j = 0; j < 4; ++j) {
      const int col = n0 + wc * 64 + j * 16 + ln15;
#pragma unroll
      for (int r = 0; r < 4; ++r) {
        float v = acc[i][j][r];
        if (col >= act_col0) v = tanhf(v + bias[col - act_col0]);
        const size_t off = (size_t)(rowb + r) * N + col;
        if (OUTF == 0) ((unsigned short*)Cout)[off] = f2b(v);
        else ((float*)Cout)[off] = v;
      }
    }
  }
}

// ---------- sensor layer 2: lc = sigmoid(h1 @ w2.T + b2) ----------
__global__ __launch_bounds__(256) void sensor2_kernel(
    const unsigned short* __restrict__ QKVH, const float* __restrict__ w2,
    const float* __restrict__ b2, float* __restrict__ LC) {
  const int tid = threadIdx.x;
  const int h = tid & 15, r = tid >> 4;
  const int m = blockIdx.x * 16 + r;
  const unsigned short* hrow = QKVH + (size_t)m * 3328 + 3072;
  const float* wrow = w2 + h * 256;
  float acc = 0.0f;
  for (int d = 0; d < 256; d += 8) {
    uint4 hv = *(const uint4*)(hrow + d);
    float4 wa = *(const float4*)(wrow + d);
    float4 wb = *(const float4*)(wrow + d + 4);
    acc = fmaf(blo(hv.x), wa.x, acc); acc = fmaf(bhi(hv.x), wa.y, acc);
    acc = fmaf(blo(hv.y), wa.z, acc); acc = fmaf(bhi(hv.y), wa.w, acc);
    acc = fmaf(blo(hv.z), wb.x, acc); acc = fmaf(bhi(hv.z), wb.y, acc);
    acc = fmaf(blo(hv.w), wb.z, acc); acc = fmaf(bhi(hv.w), wb.w, acc);
  }
  LC[(size_t)m * 16 + h] = sigf(acc + b2[h]);
}

// ---------- scan pass A (MFMA): MT[f,e] = sum_s (k[s,e]*R_s[e]) V[s,f]; P = prod lam ----------
// R_s = prod_{r>s} lam_r (suffix). All 64x64 mats live in LDS with the
// m201-style row-XOR swizzle (row=128B=8x16B slots, slot^=(row&7)) on both sides.
__global__ __launch_bounds__(256) void scan_passA_kernel(
    const unsigned short* __restrict__ QKVH, const float* __restrict__ LC,
    const float* __restrict__ decay, float* __restrict__ MT, float* __restrict__ P) {
  __shared__ char SH[34304];
  ushort* kL = (ushort*)SH;              // [64][64] bf16 (linear)
  ushort* vL = (ushort*)(SH + 8192);     // [64][64]
  char* khT  = SH + 16384;               // [e][s] bf16 swizzled
  char* vT   = SH + 24576;               // [f][s] bf16 swizzled
  float* sigL = (float*)(SH + 32768);
  float* lcL  = (float*)(SH + 33024);
  float* Lp   = (float*)(SH + 33280);    // [4][64]

  const int tid = threadIdx.x;
  const int c = blockIdx.x, h = blockIdx.y, b = blockIdx.z;
  const int t0 = c * 64;
#pragma unroll
  for (int i = 0; i < 2; ++i) {
    int idx = i * 256 + tid;
    int row = idx >> 3, ch = idx & 7;
    size_t g = (size_t)(b * 2048 + t0 + row) * 3328 + h * 64 + ch * 8;
    int lb = (i * 256 + (tid >> 6) * 64) * 16;
    llds16(QKVH + g + 1024, (char*)kL + lb);
    llds16(QKVH + g + 2048, (char*)vL + lb);
  }
  if (tid < 64) sigL[tid] = sigf(decay[h * 64 + tid]);
  else if (tid < 128) lcL[tid - 64] = LC[(size_t)(b * 2048 + t0 + tid - 64) * 16 + h];
  __syncthreads();

  const int e = tid & 63, seg = tid >> 6;
  const float sig_e = sigL[e];
  float lp = 1.f;
#pragma unroll
  for (int i = 0; i < 16; ++i)
    lp *= fminf(sig_e * (1.f + 0.2f * lcL[seg * 16 + i]), 0.9995f);
  Lp[seg * 64 + e] = lp;
  __syncthreads();
  float T = 1.f;
#pragma unroll
  for (int sg = 0; sg < 4; ++sg) if (sg > seg) T *= Lp[sg * 64 + e];

  // suffix products -> khat (bf16), written as rows of khT[e][s]
  u16x8 ka = {}, kb = {};
  float r = T;
#pragma unroll
  for (int i = 15; i >= 0; --i) {
    int s = seg * 16 + i;
    float lam = fminf(sig_e * (1.f + 0.2f * lcL[s]), 0.9995f);
    float kv = blo((unsigned)kL[s * 64 + e]) * r;
    if (i >= 8) kb[i - 8] = f2b(kv); else ka[i] = f2b(kv);
    r *= lam;
  }
  *(u16x8*)(khT + e * 128 + (((2 * seg + 0) ^ (e & 7)) * 16)) = ka;
  *(u16x8*)(khT + e * 128 + (((2 * seg + 1) ^ (e & 7)) * 16)) = kb;
  if (seg == 0) P[((size_t)((b * 16 + h) * 32 + c)) * 64 + e] = r;

  // V transpose copy -> vT[f][s]
  u16x8 va = {}, vb = {};
#pragma unroll
  for (int i = 0; i < 16; ++i) {
    unsigned short vv = vL[(seg * 16 + i) * 64 + e];
    if (i >= 8) vb[i - 8] = vv; else va[i] = vv;
  }
  *(u16x8*)(vT + e * 128 + (((2 * seg + 0) ^ (e & 7)) * 16)) = va;
  *(u16x8*)(vT + e * 128 + (((2 * seg + 1) ^ (e & 7)) * 16)) = vb;
  __syncthreads();

  const int ln15 = tid & 15, hi = (tid & 63) >> 4, w = tid >> 6;
  auto rd = [&](const char* u, int row, int ks) -> bf16x8 {
    return *(const bf16x8*)(u + row * 128 + (((ks * 4 + hi) ^ (row & 7)) * 16));
  };
  bf16x8 av0 = rd(vT, w * 16 + ln15, 0), av1 = rd(vT, w * 16 + ln15, 1);
  float* Mp = MT + ((size_t)((b * 16 + h) * 32 + c)) * 4096;
#pragma unroll
  for (int er = 0; er < 4; ++er) {
    f32x4 acc = {};
    acc = MFMA(av0, rd(khT, er * 16 + ln15, 0), acc);
    acc = MFMA(av1, rd(khT, er * 16 + ln15, 1), acc);
#pragma unroll
    for (int rr = 0; rr < 4; ++rr)
      Mp[(w * 16 + hi * 4 + rr) * 64 + er * 16 + ln15] = acc[rr];
  }
}

// ---------- scan pass B: chunk-state composition on MT[f][e], elementwise ----------
__global__ __launch_bounds__(256) void scan_passB_kernel(
    float* __restrict__ MT, const float* __restrict__ P) {
  const int bh = blockIdx.y;
  const int ef = blockIdx.x * 256 + threadIdx.x;  // f*64+e
  const int e = ef & 63;
  const size_t base = (size_t)bh * 32;
  float S = 0.0f;
  for (int c = 0; c < 32; ++c) {
    float* Mp = MT + (base + c) * 4096 + ef;
    const float p = P[(base + c) * 64 + e];
    const float m = *Mp;
    *Mp = S;
    S = fmaf(p, S, m);
  }
}

// ---------- scan pass C (MFMA): Y = Qh SinT^T + tril(Qh Kh^T) V ----------
// Qh = q * Lam_t (prefix incl.), Kh = k / Lam_s, Sin from MT (f-major).
__global__ __launch_bounds__(256) void scan_passC_kernel(
    const unsigned short* __restrict__ QKVH, const float* __restrict__ LC,
    const float* __restrict__ decay, const float* __restrict__ MT,
    unsigned short* __restrict__ Y) {
  __shared__ char SH[50688];
  ushort* qL = (ushort*)SH;              // staging (dead after qT)
  ushort* kL = (ushort*)(SH + 8192);     // staging (dead after kT)
  ushort* vL = (ushort*)(SH + 16384);
  char* qT = SH + 24576;                 // [t][e] swz
  char* kT = SH + 32768;                 // [s][e] swz
  char* vT = SH + 40960;                 // [f][s] swz
  char* Ab   = SH;                       // [t][s] swz (aliases qL)
  char* sinT = SH + 8192;                // [f][e] swz (aliases kL)
  float* sigL = (float*)(SH + 49152);
  float* lcL  = (float*)(SH + 49408);
  float* Lp   = (float*)(SH + 49664);

  const int tid = threadIdx.x;
  const int c = blockIdx.x, h = blockIdx.y, b = blockIdx.z;
  const int t0 = c * 64;
#pragma unroll
  for (int i = 0; i < 2; ++i) {
    int idx = i * 256 + tid;
    int row = idx >> 3, ch = idx & 7;
    size_t g = (size_t)(b * 2048 + t0 + row) * 3328 + h * 64 + ch * 8;
    int lb = (i * 256 + (tid >> 6) * 64) * 16;
    llds16(QKVH + g,        (char*)qL + lb);
    llds16(QKVH + g + 1024, (char*)kL + lb);
    llds16(QKVH + g + 2048, (char*)vL + lb);
  }
  if (tid < 64) sigL[tid] = sigf(decay[h * 64 + tid]);
  else if (tid < 128) lcL[tid - 64] = LC[(size_t)(b * 2048 + t0 + tid - 64) * 16 + h];
  __syncthreads();

  const int e = tid & 63, seg = tid >> 6;
  const float sig_e = sigL[e];
  float lp = 1.f;
#pragma unroll
  for (int i = 0; i < 16; ++i)
    lp *= fminf(sig_e * (1.f + 0.2f * lcL[seg * 16 + i]), 0.9995f);
  Lp[seg * 64 + e] = lp;
  __syncthreads();
  float a = 1.f;
#pragma unroll
  for (int sg = 0; sg < 4; ++sg) if (sg < seg) a *= Lp[sg * 64 + e];

  // build Qh -> qT[t][e], Kh -> kT[s][e] (row-at-a-time, conflict-free)
#pragma unroll
  for (int i = 0; i < 16; ++i) {
    int t = seg * 16 + i;
    a *= fminf(sig_e * (1.f + 0.2f * lcL[t]), 0.9995f);
    float qv = blo((unsigned)qL[t * 64 + e]) * a;
    float kv = blo((unsigned)kL[t * 64 + e]) / fmaxf(a, 1e-30f);
    int off = ((e >> 3) ^ (t & 7)) * 16 + (e & 7) * 2;
    *(unsigned short*)(qT + t * 128 + off) = f2b(qv);
    *(unsigned short*)(kT + t * 128 + off) = f2b(kv);
  }
  // V transpose -> vT[f][s]
  u16x8 va = {}, vb = {};
#pragma unroll
  for (int i = 0; i < 16; ++i) {
    unsigned short vv = vL[(seg * 16 + i) * 64 + e];
    if (i >= 8) vb[i - 8] = vv; else va[i] = vv;
  }
  *(u16x8*)(vT + e * 128 + (((2 * seg + 0) ^ (e & 7)) * 16)) = va;
  *(u16x8*)(vT + e * 128 + (((2 * seg + 1) ^ (e & 7)) * 16)) = vb;
  __syncthreads();

  const int ln15 = tid & 15, hi = (tid & 63) >> 4, w = tid >> 6;
  auto rd = [&](const char* u, int row, int ks) -> bf16x8 {
    return *(const bf16x8*)(u + row * 128 + (((ks * 4 + hi) ^ (row & 7)) * 16));
  };
  // MFMA1: A[t,s] = Qh Kh^T, tiles (tr=w, sr<=w)
  bf16x8 Aq0 = rd(qT, w * 16 + ln15, 0), Aq1 = rd(qT, w * 16 + ln15, 1);
  f32x4 acc1[4];
#pragma unroll
  for (int sr = 0; sr < 4; ++sr) {
    acc1[sr] = (f32x4){0.f, 0.f, 0.f, 0.f};
    if (sr <= w) {
      acc1[sr] = MFMA(Aq0, rd(kT, sr * 16 + ln15, 0), acc1[sr]);
      acc1[sr] = MFMA(Aq1, rd(kT, sr * 16 + ln15, 1), acc1[sr]);
    }
  }
  // mask (s<=t) -> Ab rows t=w*16.. (written+read by same wave; barrier below orders)
#pragma unroll
  for (int sr = 0; sr < 4; ++sr)
#pragma unroll
    for (int rr = 0; rr < 4; ++rr) {
      int t = w * 16 + hi * 4 + rr;
      int s = sr * 16 + ln15;
      float v = 0.f;
      if (sr <= w && s <= t) v = acc1[sr][rr];
      *(unsigned short*)(Ab + t * 128 + (((s >> 3) ^ (t & 7)) * 16) + (s & 7) * 2) = f2b(v);
    }
  // SinT build from global MT (coalesced), into kL space
  {
    const float* Ms = MT + ((size_t)((b * 16 + h) * 32 + c)) * 4096 + (tid >> 2) * 64 + (tid & 3) * 16;
    const int f2 = tid >> 2, s0 = (tid & 3) * 2;
    u16x8 sa = {}, sb = {};
#pragma unroll
    for (int j = 0; j < 4; ++j) {
      float4 m4 = *(const float4*)(Ms + j * 4);
      if (j < 2) {
        sa[j * 4 + 0] = f2b(m4.x); sa[j * 4 + 1] = f2b(m4.y);
        sa[j * 4 + 2] = f2b(m4.z); sa[j * 4 + 3] = f2b(m4.w);
      } else {
        sb[(j - 2) * 4 + 0] = f2b(m4.x); sb[(j - 2) * 4 + 1] = f2b(m4.y);
        sb[(j - 2) * 4 + 2] = f2b(m4.z); sb[(j - 2) * 4 + 3] = f2b(m4.w);
      }
    }
    *(u16x8*)(sinT + f2 * 128 + (((s0 + 0) ^ (f2 & 7)) * 16)) = sa;
    *(u16x8*)(sinT + f2 * 128 + (((s0 + 1) ^ (f2 & 7)) * 16)) = sb;
  }
  __syncthreads();

  // Y1 = Qh SinT^T ; Y2 = Ab V
  f32x4 accY[4];
#pragma unroll
  for (int fr = 0; fr < 4; ++fr) {
    accY[fr] = (f32x4){0.f, 0.f, 0.f, 0.f};
    accY[fr] = MFMA(Aq0, rd(sinT, fr * 16 + ln15, 0), accY[fr]);
    accY[fr] = MFMA(Aq1, rd(sinT, fr * 16 + ln15, 1), accY[fr]);
  }
  bf16x8 Aa0 = rd(Ab, w * 16 + ln15, 0), Aa1 = rd(Ab, w * 16 + ln15, 1);
#pragma unroll
  for (int fr = 0; fr < 4; ++fr) {
    accY[fr] = MFMA(Aa0, rd(vT, fr * 16 + ln15, 0), accY[fr]);
    accY[fr] = MFMA(Aa1, rd(vT, fr * 16 + ln15, 1), accY[fr]);
  }
#pragma unroll
  for (int fr = 0; fr < 4; ++fr)
#pragma unroll
    for (int rr = 0; rr < 4; ++rr)
      Y[(size_t)(b * 2048 + t0 + w * 16 + hi * 4 + rr) * 1024 + h * 64 + fr * 16 + ln15]
        = f2b(accY[fr][rr]);
}

// ---------- host launch ----------
extern "C" void kernel_launch(void* const* d_in, const int* in_sizes, int n_in,
                              void* d_out, int out_size, void* d_ws, size_t ws_size,
                              hipStream_t stream) {
  (void)in_sizes; (void)n_in; (void)out_size; (void)ws_size;
  const float* x     = (const float*)d_in[0];
  const float* q_w   = (const float*)d_in[1];
  const float* k_w   = (const float*)d_in[2];
  const float* v_w   = (const float*)d_in[3];
  const float* o_w   = (const float*)d_in[4];
  const float* cs_w1 = (const float*)d_in[5];
  const float* cs_b1 = (const float*)d_in[6];
  const float* cs_w2 = (const float*)d_in[7];
  const float* cs_b2 = (const float*)d_in[8];
  const float* decay = (const float*)d_in[9];
  float* out = (float*)d_out;

  char* ws = (char*)d_ws;
  unsigned short* XB   = (unsigned short*)(ws);
  unsigned short* WCAT = (unsigned short*)(ws + 16777216);
  unsigned short* OWB  = (unsigned short*)(ws + 23592960);
  unsigned short* QKVH = (unsigned short*)(ws + 25690112);
  float*          LCb  = (float*)(ws + 80216064);
  float*          MT   = (float*)(ws + 80740352);
  float*          Pb   = (float*)(ws + 114294784);
  unsigned short* YB   = (unsigned short*)(ws + 114819072);

  cvt_all_kernel<<<12544, 256, 0, stream>>>(x, q_w, k_w, v_w, cs_w1, o_w,
                                            XB, WCAT, OWB);

  gemm_bk64_kernel<0><<<1664, 256, 0, stream>>>(XB, WCAT, QKVH, 8192, 3328,
                                                1024, 3072, cs_b1, 26);
  sensor2_kernel<<<512, 256, 0, stream>>>(QKVH, cs_w2, cs_b2, LCb);

  scan_passA_kernel<<<dim3(32, 16, 4), 256, 0, stream>>>(QKVH, LCb, decay, MT, Pb);
  scan_passB_kernel<<<dim3(16, 64), 256, 0, stream>>>(MT, Pb);
  scan_passC_kernel<<<dim3(32, 16, 4), 256, 0, stream>>>(QKVH, LCb, decay, MT, YB);

  gemm_bk64_kernel<1><<<512, 256, 0, stream>>>(YB, OWB, out, 8192, 1024,
                                               1024, 1 << 30, nullptr, 8);
}

// Round 6
// 169.597 us; speedup vs baseline: 1.8472x; 1.0291x over previous
//
#include <hip/hip_runtime.h>

#define DEV __device__ __forceinline__
#define MFMA(a, b, c) __builtin_amdgcn_mfma_f32_16x16x32_bf16(a, b, c, 0, 0, 0)

typedef __bf16 bf16x8 __attribute__((ext_vector_type(8)));
typedef float f32x4 __attribute__((ext_vector_type(4)));
typedef unsigned short u16x8 __attribute__((ext_vector_type(8)));

// ---------- helpers ----------
DEV float blo(unsigned u) { return __builtin_bit_cast(float, u << 16); }
DEV float bhi(unsigned u) { return __builtin_bit_cast(float, u & 0xFFFF0000u); }
DEV unsigned short f2b(float f) {
  unsigned u = __builtin_bit_cast(unsigned, f);
  return (unsigned short)((u + 0x7FFFu + ((u >> 16) & 1u)) >> 16);
}
DEV float sigf(float x) { return 1.0f / (1.0f + expf(-x)); }

DEV void llds16(const void* g, void* l) {
  __builtin_amdgcn_global_load_lds(
      (__attribute__((address_space(1))) void*)(void*)g,
      (__attribute__((address_space(3))) void*)l, 16, 0, 0);
}

// ---------- fused fp32 -> bf16 conversion (all 6 tensors, 1 launch) ----------
__global__ __launch_bounds__(256) void cvt_all_kernel(
    const float* __restrict__ x, const float* __restrict__ qw,
    const float* __restrict__ kw, const float* __restrict__ vw,
    const float* __restrict__ cw1, const float* __restrict__ ow,
    unsigned short* __restrict__ XB, unsigned short* __restrict__ WCAT,
    unsigned short* __restrict__ OWB) {
  const int i = blockIdx.x * 256 + threadIdx.x;
  const float* s;
  unsigned short* d;
  if (i < 2097152)      { s = x   + (size_t)i * 4;                 d = XB + (size_t)i * 4; }
  else if (i < 2359296) { size_t j = i - 2097152; s = qw  + j * 4; d = WCAT + j * 4; }
  else if (i < 2621440) { size_t j = i - 2359296; s = kw  + j * 4; d = WCAT + 1048576 + j * 4; }
  else if (i < 2883584) { size_t j = i - 2621440; s = vw  + j * 4; d = WCAT + 2097152 + j * 4; }
  else if (i < 2949120) { size_t j = i - 2883584; s = cw1 + j * 4; d = WCAT + 3145728 + j * 4; }
  else if (i < 3211264) { size_t j = i - 2949120; s = ow  + j * 4; d = OWB + j * 4; }
  else return;
  float4 f = *(const float4*)s;
  ushort4 o;
  o.x = f2b(f.x); o.y = f2b(f.y); o.z = f2b(f.z); o.w = f2b(f.w);
  *(ushort4*)d = o;
}

// ---------- 128x128 GEMM, BK=64, conflict-free XOR swizzle (proven r4/r5) ----------
// C[m][n] = sum_k A[m][k]*B[n][k]. Cols >= act_col0: v=tanh(v+bias), written to
// Cout2 (dense, ld=256); else Cout with stride ldC.
template <int OUTF>  // 0 = bf16 out, 1 = fp32 out
__global__ __launch_bounds__(256, 2) void gemm_bk64_kernel(
    const unsigned short* __restrict__ A, const unsigned short* __restrict__ B,
    void* __restrict__ Cout, unsigned short* __restrict__ Cout2,
    int K, int ldC, int act_col0, const float* __restrict__ bias, int nbn) {
  __shared__ char As[16384];
  __shared__ char Bs[16384];
  const int tid = threadIdx.x;
  const int lane = tid & 63;
  const int w = tid >> 6;
  const int wr = w >> 1, wc = w & 1;
  const int ln15 = lane & 15, hi = lane >> 4;

  const int nwg = gridDim.x, orig = blockIdx.x;
  const int qd = nwg >> 3, rm = nwg & 7;
  const int xcd = orig & 7, loc = orig >> 3;
  const int swz = (xcd < rm ? xcd * (qd + 1) : rm * (qd + 1) + (xcd - rm) * qd) + loc;
  const int bn = swz % nbn, bm = swz / nbn;
  const int m0 = bm * 128, n0 = bn * 128;

  auto stage = [&](const unsigned short* src, int row0, int k0, char* dst) {
#pragma unroll
    for (int j = 0; j < 4; ++j) {
      const int slot = j * 256 + tid;
      const int rr = slot >> 3;
      const int kc = (slot & 7) ^ (rr & 7);
      llds16(src + (size_t)(row0 + rr) * K + k0 + kc * 8, dst + slot * 16);
    }
  };
  auto rd = [&](const char* unit, int row, int ks) -> bf16x8 {
    const int kc = (ks * 4 + hi) ^ (row & 7);
    return *(const bf16x8*)(unit + row * 128 + kc * 16);
  };

  f32x4 acc[4][4] = {};
  const int nk = K >> 6;
  for (int kt = 0; kt < nk; ++kt) {
    stage(A, m0, kt * 64, As);
    stage(B, n0, kt * 64, Bs);
    __syncthreads();
    bf16x8 af[2][4], bf[2][4];
#pragma unroll
    for (int ks = 0; ks < 2; ++ks)
#pragma unroll
      for (int i = 0; i < 4; ++i) {
        af[ks][i] = rd(As, wr * 64 + i * 16 + ln15, ks);
        bf[ks][i] = rd(Bs, wc * 64 + i * 16 + ln15, ks);
      }
#pragma unroll
    for (int i = 0; i < 4; ++i)
#pragma unroll
      for (int j = 0; j < 4; ++j) {
        acc[i][j] = MFMA(af[0][i], bf[0][j], acc[i][j]);
        acc[i][j] = MFMA(af[1][i], bf[1][j], acc[i][j]);
      }
    __syncthreads();
  }
#pragma unroll
  for (int i = 0; i < 4; ++i) {
    const int rowb = m0 + wr * 64 + i * 16 + hi * 4;
#pragma unroll
    for (int j = 0; j < 4; ++j) {
      const int col = n0 + wc * 64 + j * 16 + ln15;
#pragma unroll
      for (int r = 0; r < 4; ++r) {
        float v = acc[i][j][r];
        if (col >= act_col0) {
          v = tanhf(v + bias[col - act_col0]);
          Cout2[(size_t)(rowb + r) * 256 + (col - act_col0)] = f2b(v);
        } else {
          const size_t off = (size_t)(rowb + r) * ldC + col;
          if (OUTF == 0) ((unsigned short*)Cout)[off] = f2b(v);
          else ((float*)Cout)[off] = v;
        }
      }
    }
  }
}

// ---------- sensor layer 2: lc = sigmoid(h1 @ w2.T + b2), dense H1 ----------
__global__ __launch_bounds__(256) void sensor2_kernel(
    const unsigned short* __restrict__ H1, const float* __restrict__ w2,
    const float* __restrict__ b2, float* __restrict__ LC) {
  const int tid = threadIdx.x;
  const int h = tid & 15, r = tid >> 4;
  const int m = blockIdx.x * 16 + r;
  const unsigned short* hrow = H1 + (size_t)m * 256;
  const float* wrow = w2 + h * 256;
  float acc = 0.0f;
  for (int d = 0; d < 256; d += 8) {
    uint4 hv = *(const uint4*)(hrow + d);
    float4 wa = *(const float4*)(wrow + d);
    float4 wb = *(const float4*)(wrow + d + 4);
    acc = fmaf(blo(hv.x), wa.x, acc); acc = fmaf(bhi(hv.x), wa.y, acc);
    acc = fmaf(blo(hv.y), wa.z, acc); acc = fmaf(bhi(hv.y), wa.w, acc);
    acc = fmaf(blo(hv.z), wb.x, acc); acc = fmaf(bhi(hv.z), wb.y, acc);
    acc = fmaf(blo(hv.w), wb.z, acc); acc = fmaf(bhi(hv.w), wb.w, acc);
  }
  LC[(size_t)m * 16 + h] = sigf(acc + b2[h]);
}

// ---------- scan pass A (MFMA): MTB image [f][slot^f&7] bf16; P = prod lam ----------
// MTB per chunk = EXACT byte image of the swizzled sinT LDS tile (8 KB).
// element (f,e) at ushort index f*64 + ((e>>3)^(f&7))*8 + (e&7).
__global__ __launch_bounds__(256) void scan_passA_kernel(
    const unsigned short* __restrict__ QKV, const float* __restrict__ LC,
    const float* __restrict__ decay, unsigned short* __restrict__ MTB,
    float* __restrict__ P) {
  __shared__ char SH[34304];
  ushort* kL = (ushort*)SH;              // [64][64] bf16 (linear)
  ushort* vL = (ushort*)(SH + 8192);
  char* khT  = SH + 16384;               // [e][s] swz
  char* vT   = SH + 24576;               // [f][s] swz
  float* sigL = (float*)(SH + 32768);
  float* lcL  = (float*)(SH + 33024);
  float* Lp   = (float*)(SH + 33280);

  const int tid = threadIdx.x;
  const int c = blockIdx.x, h = blockIdx.y, b = blockIdx.z;
  const int t0 = c * 64;
#pragma unroll
  for (int i = 0; i < 2; ++i) {
    int idx = i * 256 + tid;
    int row = idx >> 3, ch = idx & 7;
    size_t g = (size_t)(b * 2048 + t0 + row) * 3072 + h * 64 + ch * 8;
    int lb = (i * 256 + (tid >> 6) * 64) * 16;
    llds16(QKV + g + 1024, (char*)kL + lb);
    llds16(QKV + g + 2048, (char*)vL + lb);
  }
  if (tid < 64) sigL[tid] = sigf(decay[h * 64 + tid]);
  else if (tid < 128) lcL[tid - 64] = LC[(size_t)(b * 2048 + t0 + tid - 64) * 16 + h];
  __syncthreads();

  const int e = tid & 63, seg = tid >> 6;
  const float sig_e = sigL[e];
  float lp = 1.f;
#pragma unroll
  for (int i = 0; i < 16; ++i)
    lp *= fminf(sig_e * (1.f + 0.2f * lcL[seg * 16 + i]), 0.9995f);
  Lp[seg * 64 + e] = lp;
  __syncthreads();
  float T = 1.f;
#pragma unroll
  for (int sg = 0; sg < 4; ++sg) if (sg > seg) T *= Lp[sg * 64 + e];

  // suffix products -> khat rows khT[e][s]
  u16x8 ka = {}, kb = {};
  float r = T;
#pragma unroll
  for (int i = 15; i >= 0; --i) {
    int s = seg * 16 + i;
    float lam = fminf(sig_e * (1.f + 0.2f * lcL[s]), 0.9995f);
    float kv = blo((unsigned)kL[s * 64 + e]) * r;
    if (i >= 8) kb[i - 8] = f2b(kv); else ka[i] = f2b(kv);
    r *= lam;
  }
  *(u16x8*)(khT + e * 128 + (((2 * seg + 0) ^ (e & 7)) * 16)) = ka;
  *(u16x8*)(khT + e * 128 + (((2 * seg + 1) ^ (e & 7)) * 16)) = kb;
  if (seg == 0) P[((size_t)((b * 16 + h) * 32 + c)) * 64 + e] = r;

  // V transpose -> vT[f][s]
  u16x8 va = {}, vb = {};
#pragma unroll
  for (int i = 0; i < 16; ++i) {
    unsigned short vv = vL[(seg * 16 + i) * 64 + e];
    if (i >= 8) vb[i - 8] = vv; else va[i] = vv;
  }
  *(u16x8*)(vT + e * 128 + (((2 * seg + 0) ^ (e & 7)) * 16)) = va;
  *(u16x8*)(vT + e * 128 + (((2 * seg + 1) ^ (e & 7)) * 16)) = vb;
  __syncthreads();

  const int ln15 = tid & 15, hi = (tid & 63) >> 4, w = tid >> 6;
  auto rd = [&](const char* u, int row, int ks) -> bf16x8 {
    return *(const bf16x8*)(u + row * 128 + (((ks * 4 + hi) ^ (row & 7)) * 16));
  };
  bf16x8 av0 = rd(vT, w * 16 + ln15, 0), av1 = rd(vT, w * 16 + ln15, 1);
  unsigned short* Mp = MTB + ((size_t)((b * 16 + h) * 32 + c)) * 4096;
#pragma unroll
  for (int er = 0; er < 4; ++er) {
    f32x4 acc = {};
    acc = MFMA(av0, rd(khT, er * 16 + ln15, 0), acc);
    acc = MFMA(av1, rd(khT, er * 16 + ln15, 1), acc);
    const int e2 = er * 16 + ln15;
#pragma unroll
    for (int rr = 0; rr < 4; ++rr) {
      const int f = w * 16 + hi * 4 + rr;
      Mp[f * 64 + (((e2 >> 3) ^ (f & 7)) << 3) + (e2 & 7)] = f2b(acc[rr]);
    }
  }
}

// ---------- scan pass B: chunk-state composition on bf16 image, fp32 carry ----------
__global__ __launch_bounds__(256) void scan_passB_kernel(
    unsigned short* __restrict__ MTB, const float* __restrict__ P) {
  const int bh = blockIdx.y;
  const int task = blockIdx.x * 256 + threadIdx.x;  // 0..4095 = f*64+slot*8+pos
  const int f = task >> 6, slot = (task >> 3) & 7, pos = task & 7;
  const int e = ((slot ^ (f & 7)) << 3) | pos;
  const size_t base = (size_t)bh * 32;
  float S = 0.0f;
  for (int c = 0; c < 32; ++c) {
    unsigned short* Mp = MTB + (base + c) * 4096 + task;
    const float p = P[(base + c) * 64 + e];
    const float m = blo((unsigned)*Mp);
    *Mp = f2b(S);
    S = fmaf(p, S, m);
  }
}

// ---------- scan pass C (MFMA): Y = Qh SinT^T + tril(Qh Kh^T) V ----------
__global__ __launch_bounds__(256) void scan_passC_kernel(
    const unsigned short* __restrict__ QKV, const float* __restrict__ LC,
    const float* __restrict__ decay, const unsigned short* __restrict__ MTB,
    unsigned short* __restrict__ Y) {
  __shared__ char SH[50688];
  ushort* qL = (ushort*)SH;              // staging (dead after P2)
  ushort* kL = (ushort*)(SH + 8192);     // staging (dead after P2)
  ushort* vL = (ushort*)(SH + 16384);
  char* qT = SH + 24576;                 // [t][e] swz
  char* kT = SH + 32768;                 // [s][e] swz
  char* vT = SH + 40960;                 // [f][s] swz
  char* Ab   = SH;                       // [t][s] swz (aliases qL)
  char* sinT = SH + 8192;                // [f][e] swz (aliases kL)
  float* sigL = (float*)(SH + 49152);
  float* lcL  = (float*)(SH + 49408);
  float* Lp   = (float*)(SH + 49664);

  const int tid = threadIdx.x;
  const int c = blockIdx.x, h = blockIdx.y, b = blockIdx.z;
  const int t0 = c * 64;
#pragma unroll
  for (int i = 0; i < 2; ++i) {
    int idx = i * 256 + tid;
    int row = idx >> 3, ch = idx & 7;
    size_t g = (size_t)(b * 2048 + t0 + row) * 3072 + h * 64 + ch * 8;
    int lb = (i * 256 + (tid >> 6) * 64) * 16;
    llds16(QKV + g,        (char*)qL + lb);
    llds16(QKV + g + 1024, (char*)kL + lb);
    llds16(QKV + g + 2048, (char*)vL + lb);
  }
  if (tid < 64) sigL[tid] = sigf(decay[h * 64 + tid]);
  else if (tid < 128) lcL[tid - 64] = LC[(size_t)(b * 2048 + t0 + tid - 64) * 16 + h];
  __syncthreads();

  // ---- P2: decay products; build Qh->qT, Kh->kT, V->vT
  const int e = tid & 63, seg = tid >> 6;
  const float sig_e = sigL[e];
  float lp = 1.f;
#pragma unroll
  for (int i = 0; i < 16; ++i)
    lp *= fminf(sig_e * (1.f + 0.2f * lcL[seg * 16 + i]), 0.9995f);
  Lp[seg * 64 + e] = lp;
  __syncthreads();
  float a = 1.f;
#pragma unroll
  for (int sg = 0; sg < 4; ++sg) if (sg < seg) a *= Lp[sg * 64 + e];

#pragma unroll
  for (int i = 0; i < 16; ++i) {
    int t = seg * 16 + i;
    a *= fminf(sig_e * (1.f + 0.2f * lcL[t]), 0.9995f);
    float qv = blo((unsigned)qL[t * 64 + e]) * a;
    float kv = blo((unsigned)kL[t * 64 + e]) / fmaxf(a, 1e-30f);
    int off = ((e >> 3) ^ (t & 7)) * 16 + (e & 7) * 2;
    *(unsigned short*)(qT + t * 128 + off) = f2b(qv);
    *(unsigned short*)(kT + t * 128 + off) = f2b(kv);
  }
  u16x8 va = {}, vb = {};
#pragma unroll
  for (int i = 0; i < 16; ++i) {
    unsigned short vv = vL[(seg * 16 + i) * 64 + e];
    if (i >= 8) vb[i - 8] = vv; else va[i] = vv;
  }
  *(u16x8*)(vT + e * 128 + (((2 * seg + 0) ^ (e & 7)) * 16)) = va;
  *(u16x8*)(vT + e * 128 + (((2 * seg + 1) ^ (e & 7)) * 16)) = vb;
  __syncthreads();

  // ---- P3: stage SinT image async (kL dead now); QK^T MFMA; mask -> Ab
  {
    const unsigned short* Ms = MTB + ((size_t)((b * 16 + h) * 32 + c)) * 4096;
#pragma unroll
    for (int i = 0; i < 2; ++i)
      llds16(Ms + (size_t)(i * 256 + tid) * 8, sinT + (i * 256 + (tid >> 6) * 64) * 16);
  }
  const int ln15 = tid & 15, hi = (tid & 63) >> 4, w = tid >> 6;
  auto rd = [&](const char* u, int row, int ks) -> bf16x8 {
    return *(const bf16x8*)(u + row * 128 + (((ks * 4 + hi) ^ (row & 7)) * 16));
  };
  bf16x8 Aq0 = rd(qT, w * 16 + ln15, 0), Aq1 = rd(qT, w * 16 + ln15, 1);
  f32x4 acc1[4];
#pragma unroll
  for (int sr = 0; sr < 4; ++sr) {
    acc1[sr] = (f32x4){0.f, 0.f, 0.f, 0.f};
    if (sr <= w) {
      acc1[sr] = MFMA(Aq0, rd(kT, sr * 16 + ln15, 0), acc1[sr]);
      acc1[sr] = MFMA(Aq1, rd(kT, sr * 16 + ln15, 1), acc1[sr]);
    }
  }
#pragma unroll
  for (int sr = 0; sr < 4; ++sr)
#pragma unroll
    for (int rr = 0; rr < 4; ++rr) {
      int t = w * 16 + hi * 4 + rr;
      int s = sr * 16 + ln15;
      float v = 0.f;
      if (sr <= w && s <= t) v = acc1[sr][rr];
      *(unsigned short*)(Ab + t * 128 + (((s >> 3) ^ (t & 7)) * 16) + (s & 7) * 2) = f2b(v);
    }
  bf16x8 Aa0 = rd(Ab, w * 16 + ln15, 0), Aa1 = rd(Ab, w * 16 + ln15, 1);  // intra-wave
  __syncthreads();  // drains sinT llds16 + vT visibility

  // ---- P4: Y = Qh SinT^T + Ab V
  f32x4 accY[4];
#pragma unroll
  for (int fr = 0; fr < 4; ++fr) {
    accY[fr] = (f32x4){0.f, 0.f, 0.f, 0.f};
    accY[fr] = MFMA(Aq0, rd(sinT, fr * 16 + ln15, 0), accY[fr]);
    accY[fr] = MFMA(Aq1, rd(sinT, fr * 16 + ln15, 1), accY[fr]);
    accY[fr] = MFMA(Aa0, rd(vT, fr * 16 + ln15, 0), accY[fr]);
    accY[fr] = MFMA(Aa1, rd(vT, fr * 16 + ln15, 1), accY[fr]);
  }
#pragma unroll
  for (int fr = 0; fr < 4; ++fr)
#pragma unroll
    for (int rr = 0; rr < 4; ++rr)
      Y[(size_t)(b * 2048 + t0 + w * 16 + hi * 4 + rr) * 1024 + h * 64 + fr * 16 + ln15]
        = f2b(accY[fr][rr]);
}

// ---------- host launch ----------
extern "C" void kernel_launch(void* const* d_in, const int* in_sizes, int n_in,
                              void* d_out, int out_size, void* d_ws, size_t ws_size,
                              hipStream_t stream) {
  (void)in_sizes; (void)n_in; (void)out_size; (void)ws_size;
  const float* x     = (const float*)d_in[0];
  const float* q_w   = (const float*)d_in[1];
  const float* k_w   = (const float*)d_in[2];
  const float* v_w   = (const float*)d_in[3];
  const float* o_w   = (const float*)d_in[4];
  const float* cs_w1 = (const float*)d_in[5];
  const float* cs_b1 = (const float*)d_in[6];
  const float* cs_w2 = (const float*)d_in[7];
  const float* cs_b2 = (const float*)d_in[8];
  const float* decay = (const float*)d_in[9];
  float* out = (float*)d_out;

  char* ws = (char*)d_ws;
  unsigned short* XB   = (unsigned short*)(ws);                 // 16,777,216
  unsigned short* WCAT = (unsigned short*)(ws + 16777216);      //  6,815,744
  unsigned short* OWB  = (unsigned short*)(ws + 23592960);      //  2,097,152
  unsigned short* QKV  = (unsigned short*)(ws + 25690112);      // 50,331,648 (stride 3072)
  unsigned short* H1   = (unsigned short*)(ws + 76021760);      //  4,194,304
  float*          LCb  = (float*)(ws + 80216064);               //    524,288
  unsigned short* MTB  = (unsigned short*)(ws + 80740352);      // 16,777,216 (bf16 image)
  float*          Pb   = (float*)(ws + 97517568);               //    524,288
  unsigned short* YB   = (unsigned short*)(ws + 98041856);      // 16,777,216

  cvt_all_kernel<<<12544, 256, 0, stream>>>(x, q_w, k_w, v_w, cs_w1, o_w,
                                            XB, WCAT, OWB);

  // fused q|k|v|h1 GEMM: [8192x1024]@[3328x1024]^T; qkv->QKV(ld 3072), h1->H1
  gemm_bk64_kernel<0><<<1664, 256, 0, stream>>>(XB, WCAT, QKV, H1,
                                                1024, 3072, 3072, cs_b1, 26);
  sensor2_kernel<<<512, 256, 0, stream>>>(H1, cs_w2, cs_b2, LCb);

  scan_passA_kernel<<<dim3(32, 16, 4), 256, 0, stream>>>(QKV, LCb, decay, MTB, Pb);
  scan_passB_kernel<<<dim3(16, 64), 256, 0, stream>>>(MTB, Pb);
  scan_passC_kernel<<<dim3(32, 16, 4), 256, 0, stream>>>(QKV, LCb, decay, MTB, YB);

  gemm_bk64_kernel<1><<<512, 256, 0, stream>>>(YB, OWB, out, nullptr,
                                               1024, 1024, 1 << 30, nullptr, 8);
}